// Round 2
// baseline (683.032 us; speedup 1.0000x reference)
//
#include <hip/hip_runtime.h>
#include <hip/hip_bf16.h>

#define NPTS 524288   // 64 * 8192
#define NBATCH 64

typedef __attribute__((ext_vector_type(8))) short bf16x8;
typedef __attribute__((ext_vector_type(4))) float f32x4;
typedef const float* __restrict__ fp;

__device__ __forceinline__ __hip_bfloat16 f2b(float v) { return __float2bfloat16(v); }

// order-preserving float<->uint key for atomicMax/Min over signed floats
__device__ __forceinline__ unsigned fkey(float f) {
    unsigned u = __float_as_uint(f);
    return u ^ ((u & 0x80000000u) ? 0xFFFFFFFFu : 0x80000000u);
}
__device__ __forceinline__ float funkey(unsigned k) {
    unsigned u = (k & 0x80000000u) ? (k ^ 0x80000000u) : ~k;
    return __uint_as_float(u);
}

// ---------------- K0: convert W2/W3 to bf16 once ----------------------------
__global__ void k_prep(fp W2, fp W3, __hip_bfloat16* __restrict__ W2b,
                       __hip_bfloat16* __restrict__ W3b)
{
    int i = blockIdx.x * blockDim.x + threadIdx.x;
    if (i < 8192) W2b[i] = f2b(W2[i]);
    const int j = i - 8192;
    if (j >= 0 && j < 32768) W3b[j] = f2b(W3[j]);
}

// ---------------- K1: second-order moments of pcd (analytic BN1 stats) ------
__launch_bounds__(256)
__global__ void k_moments(fp pcd, float* __restrict__ mom)
{
    float s[9];
#pragma unroll
    for (int i = 0; i < 9; ++i) s[i] = 0.f;
    const int stride = gridDim.x * blockDim.x;
    for (int p = blockIdx.x * blockDim.x + threadIdx.x; p < NPTS; p += stride) {
        const float x = pcd[3*p+0], y = pcd[3*p+1], z = pcd[3*p+2];
        s[0] += x; s[1] += y; s[2] += z;
        s[3] = fmaf(x, x, s[3]); s[4] = fmaf(x, y, s[4]); s[5] = fmaf(x, z, s[5]);
        s[6] = fmaf(y, y, s[6]); s[7] = fmaf(y, z, s[7]); s[8] = fmaf(z, z, s[8]);
    }
#pragma unroll
    for (int off = 1; off < 64; off <<= 1) {
#pragma unroll
        for (int i = 0; i < 9; ++i) s[i] += __shfl_xor(s[i], off);
    }
    __shared__ float red[4][9];
    const int lane = threadIdx.x & 63, wv = threadIdx.x >> 6;
    if (lane == 0) {
#pragma unroll
        for (int i = 0; i < 9; ++i) red[wv][i] = s[i];
    }
    __syncthreads();
    if (threadIdx.x < 9) {
        const int i = threadIdx.x;
        atomicAdd(&mom[i], red[0][i] + red[1][i] + red[2][i] + red[3][i]);
    }
}

// ---------------- K2: analytic BN1 scale/shift ------------------------------
__global__ void k_fin1(const float* __restrict__ mom, fp W1, fp b1, fp g1, fp be1,
                       float* __restrict__ s1, float* __restrict__ t1)
{
    const int c = threadIdx.x;  // 64 threads
    const float inv = 1.f / (float)NPTS;
    const float m0 = mom[0]*inv, m1 = mom[1]*inv, m2 = mom[2]*inv;
    const float c00 = mom[3]*inv - m0*m0, c01 = mom[4]*inv - m0*m1, c02 = mom[5]*inv - m0*m2;
    const float c11 = mom[6]*inv - m1*m1, c12 = mom[7]*inv - m1*m2, c22 = mom[8]*inv - m2*m2;
    const float w0 = W1[c*3+0], w1 = W1[c*3+1], w2 = W1[c*3+2];
    const float mu = w0*m0 + w1*m1 + w2*m2 + b1[c];
    float var = w0*w0*c00 + w1*w1*c11 + w2*w2*c22 + 2.f*(w0*w1*c01 + w0*w2*c02 + w1*w2*c12);
    var = fmaxf(var, 0.f);
    const float sc = g1[c] * rsqrtf(var + 1e-5f);
    s1[c] = sc;
    t1[c] = be1[c] - mu*sc;
}

// ---------------- fused point-MLP tile kernel -------------------------------
// Block = 256 threads = 4 waves, 64 points/block.
// DO_L3=false: L1 -> L2, accumulate y2 stats.
// DO_L3=true : L1 -> L2 -> BN2+relu -> L3, y3 stats + per-(batch,ch) min/max.
template<bool DO_L3>
__launch_bounds__(256)
__global__ void k_fused(fp pcd, fp W1, fp b1,
                        const float* __restrict__ s1, const float* __restrict__ t1,
                        const __hip_bfloat16* __restrict__ W2, fp b2,
                        float* __restrict__ st2s, float* __restrict__ st2q,
                        const float* __restrict__ s2, const float* __restrict__ t2,
                        const __hip_bfloat16* __restrict__ W3, fp b3,
                        float* __restrict__ st3s, float* __restrict__ st3q,
                        unsigned* __restrict__ maxk, unsigned* __restrict__ mink)
{
    __shared__ alignas(16) __hip_bfloat16 x1s[64*72];    // stride 72
    __shared__ alignas(16) __hip_bfloat16 x2s[64*136];   // stride 136; reused as reduce buf
    __shared__ float pcds[64*4];
    float* red = (float*)x2s;

    const int tid = threadIdx.x;
    const int blk = blockIdx.x;

    if (tid < 192) {
        const float v = pcd[(size_t)blk*192 + tid];
        pcds[(tid/3)*4 + (tid%3)] = v;
    }
    __syncthreads();

    // layer1 (fp32 VALU): pt = tid>>2, this thread does 16 channels
    {
        const int pt = tid >> 2, grp = tid & 3;
        const float px = pcds[pt*4+0], py = pcds[pt*4+1], pz = pcds[pt*4+2];
#pragma unroll
        for (int h = 0; h < 2; ++h) {
            union { bf16x8 v; __hip_bfloat16 e[8]; } u;
#pragma unroll
            for (int j = 0; j < 8; ++j) {
                const int c = grp*16 + h*8 + j;
                float y = b1[c];
                y = fmaf(px, W1[c*3+0], y);
                y = fmaf(py, W1[c*3+1], y);
                y = fmaf(pz, W1[c*3+2], y);
                u.e[j] = f2b(fmaxf(fmaf(y, s1[c], t1[c]), 0.f));
            }
            *(bf16x8*)&x1s[pt*72 + grp*16 + h*8] = u.v;
        }
    }
    __syncthreads();

    const int lane = tid & 63, wv = tid >> 6;
    const int m = lane & 15, q = lane >> 4;     // MFMA: m within 16, q = quad
    const int ptA = wv*16 + m;

    // layer2: 16(M) x 128(N) x 64(K) per wave via mfma_16x16x32_bf16
    bf16x8 a2[2];
    a2[0] = *(const bf16x8*)&x1s[ptA*72 + 0*32 + q*8];
    a2[1] = *(const bf16x8*)&x1s[ptA*72 + 1*32 + q*8];
    f32x4 acc2[8];
#pragma unroll
    for (int nt = 0; nt < 8; ++nt) acc2[nt] = (f32x4){0.f,0.f,0.f,0.f};
#pragma unroll
    for (int nt = 0; nt < 8; ++nt) {
        const __hip_bfloat16* wr = W2 + (nt*16 + m)*64 + q*8;   // B[k][n] = W2[n][k]
        const bf16x8 wb0 = *(const bf16x8*)(wr);
        const bf16x8 wb1 = *(const bf16x8*)(wr + 32);
        acc2[nt] = __builtin_amdgcn_mfma_f32_16x16x32_bf16(a2[0], wb0, acc2[nt], 0, 0, 0);
        acc2[nt] = __builtin_amdgcn_mfma_f32_16x16x32_bf16(a2[1], wb1, acc2[nt], 0, 0, 0);
    }

    if (!DO_L3) {
        // y2 stats (sum, sumsq per channel)
#pragma unroll
        for (int nt = 0; nt < 8; ++nt) {
            const int ch = nt*16 + m;
            const float bbias = b2[ch];
            float s = 0.f, ss = 0.f;
#pragma unroll
            for (int r = 0; r < 4; ++r) { const float v = acc2[nt][r] + bbias; s += v; ss = fmaf(v, v, ss); }
            s += __shfl_xor(s, 16); ss += __shfl_xor(ss, 16);
            s += __shfl_xor(s, 32); ss += __shfl_xor(ss, 32);
            if (q == 0) { red[(wv*128 + ch)*2+0] = s; red[(wv*128 + ch)*2+1] = ss; }
        }
        __syncthreads();
        if (tid < 128) {
            float s = 0.f, ss = 0.f;
#pragma unroll
            for (int w4 = 0; w4 < 4; ++w4) { s += red[(w4*128 + tid)*2]; ss += red[(w4*128 + tid)*2+1]; }
            const int slot = blk & 63;
            atomicAdd(&st2s[slot*128 + tid], s);
            atomicAdd(&st2q[slot*128 + tid], ss);
        }
        return;
    }

    // BN2 + relu -> x2 (bf16 in LDS, A-layout rows)
#pragma unroll
    for (int nt = 0; nt < 8; ++nt) {
        const int ch = nt*16 + m;
        const float bbias = b2[ch];
        const float sc = s2[ch], sh = t2[ch];
#pragma unroll
        for (int r = 0; r < 4; ++r) {
            const int pt = wv*16 + q*4 + r;   // C/D: row = q*4+r, col = m
            x2s[pt*136 + ch] = f2b(fmaxf(fmaf(acc2[nt][r] + bbias, sc, sh), 0.f));
        }
    }
    __syncthreads();

    // layer3: 16(M) x 256(N) x 128(K) per wave
    bf16x8 a3[4];
#pragma unroll
    for (int ks = 0; ks < 4; ++ks) a3[ks] = *(const bf16x8*)&x2s[ptA*136 + ks*32 + q*8];
    f32x4 acc3[16];
#pragma unroll
    for (int nt = 0; nt < 16; ++nt) acc3[nt] = (f32x4){0.f,0.f,0.f,0.f};
#pragma unroll
    for (int nt = 0; nt < 16; ++nt) {
        const __hip_bfloat16* wr = W3 + (nt*16 + m)*128 + q*8;
#pragma unroll
        for (int ks = 0; ks < 4; ++ks) {
            const bf16x8 wb = *(const bf16x8*)(wr + ks*32);
            acc3[nt] = __builtin_amdgcn_mfma_f32_16x16x32_bf16(a3[ks], wb, acc3[nt], 0, 0, 0);
        }
    }
    __syncthreads();   // everyone done reading x2s; safe to reuse as `red`

    // y3 stats + per-(batch,ch) min/max (BN3+relu+max folded later)
#pragma unroll
    for (int nt = 0; nt < 16; ++nt) {
        const int ch = nt*16 + m;
        const float bbias = b3[ch];
        float s = 0.f, ss = 0.f, mx = -3.4e38f, mn = 3.4e38f;
#pragma unroll
        for (int r = 0; r < 4; ++r) {
            const float v = acc3[nt][r] + bbias;
            s += v; ss = fmaf(v, v, ss); mx = fmaxf(mx, v); mn = fminf(mn, v);
        }
        s += __shfl_xor(s, 16); ss += __shfl_xor(ss, 16);
        mx = fmaxf(mx, __shfl_xor(mx, 16)); mn = fminf(mn, __shfl_xor(mn, 16));
        s += __shfl_xor(s, 32); ss += __shfl_xor(ss, 32);
        mx = fmaxf(mx, __shfl_xor(mx, 32)); mn = fminf(mn, __shfl_xor(mn, 32));
        if (q == 0) {
            float* rp = &red[(wv*256 + ch)*4];
            rp[0] = s; rp[1] = ss; rp[2] = mx; rp[3] = mn;
        }
    }
    __syncthreads();
    {
        float s = 0.f, ss = 0.f, mx = -3.4e38f, mn = 3.4e38f;
#pragma unroll
        for (int w4 = 0; w4 < 4; ++w4) {
            const float* rp = &red[(w4*256 + tid)*4];
            s += rp[0]; ss += rp[1]; mx = fmaxf(mx, rp[2]); mn = fminf(mn, rp[3]);
        }
        const int slot = blk & 63;
        atomicAdd(&st3s[slot*256 + tid], s);
        atomicAdd(&st3q[slot*256 + tid], ss);
        const int bat = blk >> 7;   // 128 blocks per batch
        atomicMax(&maxk[bat*256 + tid], fkey(mx));
        atomicMin(&mink[bat*256 + tid], fkey(mn));
    }
}

// ---------------- K4: finalize BN2 ------------------------------------------
__global__ void k_fin2(const float* __restrict__ sum, const float* __restrict__ sq,
                       fp g, fp be, float* __restrict__ sOut, float* __restrict__ tOut)
{
    const int ch = threadIdx.x;  // 128
    float s = 0.f, ss = 0.f;
    for (int slot = 0; slot < 64; ++slot) { s += sum[slot*128 + ch]; ss += sq[slot*128 + ch]; }
    const float inv = 1.f / (float)NPTS;
    const float mu = s * inv;
    const float var = fmaxf(ss * inv - mu*mu, 0.f);
    const float sc = g[ch] * rsqrtf(var + 1e-5f);
    sOut[ch] = sc;
    tOut[ch] = be[ch] - mu*sc;
}

// ---------------- K6: finalize BN3 + fold BN3/relu into stored min/max ------
__global__ void k_fin3(const float* __restrict__ sum, const float* __restrict__ sq,
                       fp g, fp be, const unsigned* __restrict__ maxk,
                       const unsigned* __restrict__ mink, float* __restrict__ pre)
{
    const int ch = threadIdx.x;  // 256
    float s = 0.f, ss = 0.f;
    for (int slot = 0; slot < 64; ++slot) { s += sum[slot*256 + ch]; ss += sq[slot*256 + ch]; }
    const float inv = 1.f / (float)NPTS;
    const float mu = s * inv;
    const float var = fmaxf(ss * inv - mu*mu, 0.f);
    const float sc = g[ch] * rsqrtf(var + 1e-5f);
    const float sh = be[ch] - mu*sc;
    for (int b = 0; b < NBATCH; ++b) {
        const float fmx = funkey(maxk[b*256 + ch]);
        const float fmn = funkey(mink[b*256 + ch]);
        const float pick = (sc >= 0.f) ? fmx : fmn;   // max_n relu(s*y+t) = relu(s*ext(y)+t)
        pre[b*256 + ch] = fmaxf(fmaf(pick, sc, sh), 0.f);
    }
}

// ---------------- K8: heads + QP (1 block / batch) --------------------------
__launch_bounds__(128)
__global__ void k_head(const float* __restrict__ pre,
                       fp Wfc, fp bfc, fp Wc1, fp bc1, fp Wc2, fp bc2,
                       fp Wp1, fp bp1, fp Wp2, fp bp2,
                       float* __restrict__ out)
{
    __shared__ float pf[256], ft[128], hcs[128], hps[64], ocs[48], nrm[36], hS[12], pp[8];
    const int bb = blockIdx.x, tid = threadIdx.x;
    pf[tid] = pre[bb*256 + tid];
    pf[tid+128] = pre[bb*256 + 128 + tid];
    __syncthreads();
    {
        float a = bfc[tid];
        const float* wr = Wfc + tid*256;
        for (int k = 0; k < 256; ++k) a = fmaf(pf[k], wr[k], a);
        ft[tid] = a;
    }
    __syncthreads();
    {
        float a = bc1[tid];
        const float* wr = Wc1 + tid*128;
        for (int k = 0; k < 128; ++k) a = fmaf(ft[k], wr[k], a);
        hcs[tid] = fmaxf(a, 0.f);
    }
    if (tid < 64) {
        float a = bp1[tid];
        const float* wr = Wp1 + tid*128;
        for (int k = 0; k < 128; ++k) a = fmaf(ft[k], wr[k], a);
        hps[tid] = fmaxf(a, 0.f);
    }
    __syncthreads();
    if (tid < 48) {
        float a = bc2[tid];
        const float* wr = Wc2 + tid*128;
        for (int k = 0; k < 128; ++k) a = fmaf(hcs[k], wr[k], a);
        ocs[tid] = a;
    }
    if (tid < 7) {
        float a = bp2[tid];
        const float* wr = Wp2 + tid*64;
        for (int k = 0; k < 64; ++k) a = fmaf(hps[k], wr[k], a);
        const float sc = (tid < 3) ? 0.1f : ((tid < 6) ? 1.57f : 0.05f);
        pp[tid] = tanhf(a) * sc;
    }
    __syncthreads();
    if (tid < 12) {
        float nx = ocs[tid*4+0], ny = ocs[tid*4+1], nz = ocs[tid*4+2];
        const float nn = fmaxf(sqrtf(nx*nx + ny*ny + nz*nz), 1e-12f);
        const float inv = 1.f / nn;
        nx *= inv; ny *= inv; nz *= inv;
        nrm[tid*3+0] = nx; nrm[tid*3+1] = ny; nrm[tid*3+2] = nz;
        const float xx = ocs[tid*4+3];
        hS[tid] = ((xx > 20.f) ? xx : log1pf(expf(xx))) + 0.005f;
    }
    __syncthreads();

    // QP: 500 projected-gradient iterations; lanes 0..11 own lam_c.
    const int lane = tid & 63;
    const int c = (lane < 12) ? lane : 11;
    const float n0 = nrm[c*3+0], n1 = nrm[c*3+1], n2 = nrm[c*3+2];
    float Mrow[12];
    float trace = 0.f;
#pragma unroll
    for (int d = 0; d < 12; ++d) {
        const float d0 = nrm[d*3+0], d1 = nrm[d*3+1], d2 = nrm[d*3+2];
        Mrow[d] = n0*d0 + n1*d1 + n2*d2 + ((d == lane) ? 5e-4f : 0.f);
        trace += d0*d0 + d1*d1 + d2*d2;
    }
    const float alpha = 1.f / (trace + 12.f*5e-4f);
    const float qc = n0*pp[0] + n1*pp[1] + n2*pp[2] - hS[c];
    float lam = 0.f;
    for (int it = 0; it < 500; ++it) {
        const float l0 = __shfl(lam, 0),  l1 = __shfl(lam, 1),  l2 = __shfl(lam, 2);
        const float l3 = __shfl(lam, 3),  l4 = __shfl(lam, 4),  l5 = __shfl(lam, 5);
        const float l6 = __shfl(lam, 6),  l7 = __shfl(lam, 7),  l8 = __shfl(lam, 8);
        const float l9 = __shfl(lam, 9),  l10 = __shfl(lam, 10), l11 = __shfl(lam, 11);
        const float g0 = fmaf(Mrow[0], l0, fmaf(Mrow[3], l3, fmaf(Mrow[6], l6, Mrow[9]*l9)));
        const float g1 = fmaf(Mrow[1], l1, fmaf(Mrow[4], l4, fmaf(Mrow[7], l7, Mrow[10]*l10)));
        const float g2 = fmaf(Mrow[2], l2, fmaf(Mrow[5], l5, fmaf(Mrow[8], l8, Mrow[11]*l11)));
        lam = fmaxf(fmaf(-alpha, g0 + g1 + g2 - qc, lam), 0.f);
    }
    float v0 = (lane < 12) ? n0*lam : 0.f;
    float v1 = (lane < 12) ? n1*lam : 0.f;
    float v2 = (lane < 12) ? n2*lam : 0.f;
#pragma unroll
    for (int off = 1; off <= 8; off <<= 1) {
        v0 += __shfl_xor(v0, off);
        v1 += __shfl_xor(v1, off);
        v2 += __shfl_xor(v2, off);
    }
    // outputs: delta_norm(64x7) | normals(64x12x3) | h(64x12) | p_pred(64x7)
    if (tid < 7) {
        float z;
        if (tid == 0) z = pp[0] - v0;
        else if (tid == 1) z = pp[1] - v1;
        else if (tid == 2) z = pp[2] - v2;
        else z = pp[tid];
        out[bb*7 + tid] = z;
    }
    if (tid < 36) out[448 + bb*36 + tid] = nrm[tid];
    if (tid < 12) out[2752 + bb*12 + tid] = hS[tid];
    if (tid < 7)  out[3520 + bb*7 + tid] = pp[tid];
}

// ---------------- host ------------------------------------------------------
extern "C" void kernel_launch(void* const* d_in, const int* in_sizes, int n_in,
                              void* d_out, int out_size, void* d_ws, size_t ws_size,
                              hipStream_t stream) {
    fp pcd = (fp)d_in[0];
    fp W1 = (fp)d_in[1],  b1 = (fp)d_in[2],  g1 = (fp)d_in[3],  be1 = (fp)d_in[4];
    fp W2 = (fp)d_in[5],  b2 = (fp)d_in[6],  g2 = (fp)d_in[7],  be2 = (fp)d_in[8];
    fp W3 = (fp)d_in[9],  b3 = (fp)d_in[10], g3 = (fp)d_in[11], be3 = (fp)d_in[12];
    fp Wfc = (fp)d_in[13], bfc = (fp)d_in[14];
    fp Wc1 = (fp)d_in[15], bc1 = (fp)d_in[16];
    fp Wc2 = (fp)d_in[17], bc2 = (fp)d_in[18];
    fp Wp1 = (fp)d_in[19], bp1 = (fp)d_in[20];
    fp Wp2 = (fp)d_in[21], bp2 = (fp)d_in[22];

    float* ws = (float*)d_ws;
    float* mom  = ws + 0;          // 16
    float* s1   = ws + 16;         // 64
    float* t1   = ws + 80;         // 64
    float* s2   = ws + 144;        // 128
    float* t2   = ws + 272;        // 128
    float* pre  = ws + 912;        // 64*256
    float* st2s = ws + 17296;      // 64*128
    float* st2q = ws + 25488;      // 64*128
    float* st3s = ws + 33680;      // 64*256
    float* st3q = ws + 50064;      // 64*256
    unsigned* maxk = (unsigned*)(ws + 66448);  // 64*256 (init 0 = fkey(-max))
    unsigned* mink = (unsigned*)(ws + 82832);  // 64*256 (init 0xFFFFFFFF)
    __hip_bfloat16* W2b = (__hip_bfloat16*)(ws + 99216);   // 8192 bf16
    __hip_bfloat16* W3b = (__hip_bfloat16*)(ws + 103312);  // 32768 bf16
    if (ws_size < (size_t)119696 * 4) return;

    hipMemsetAsync(d_ws, 0, (size_t)82832 * 4, stream);
    hipMemsetAsync((void*)mink, 0xFF, (size_t)16384 * 4, stream);

    k_prep<<<160, 256, 0, stream>>>(W2, W3, W2b, W3b);
    k_moments<<<256, 256, 0, stream>>>(pcd, mom);
    k_fin1<<<1, 64, 0, stream>>>(mom, W1, b1, g1, be1, s1, t1);
    k_fused<false><<<8192, 256, 0, stream>>>(pcd, W1, b1, s1, t1, W2b, b2, st2s, st2q,
                                             s2, t2, W3b, b3, st3s, st3q, maxk, mink);
    k_fin2<<<1, 128, 0, stream>>>(st2s, st2q, g2, be2, s2, t2);
    k_fused<true><<<8192, 256, 0, stream>>>(pcd, W1, b1, s1, t1, W2b, b2, st2s, st2q,
                                            s2, t2, W3b, b3, st3s, st3q, maxk, mink);
    k_fin3<<<1, 256, 0, stream>>>(st3s, st3q, g3, be3, maxk, mink, pre);
    k_head<<<64, 128, 0, stream>>>(pre, Wfc, bfc, Wc1, bc1, Wc2, bc2,
                                   Wp1, bp1, Wp2, bp2, (float*)d_out);
}

// Round 4
// 328.571 us; speedup vs baseline: 2.0788x; 2.0788x over previous
//
#include <hip/hip_runtime.h>
#include <hip/hip_bf16.h>

#define NPTS 524288   // 64 * 8192
#define NBATCH 64

typedef __attribute__((ext_vector_type(8))) short bf16x8;
typedef __attribute__((ext_vector_type(4))) float f32x4;
typedef const float* __restrict__ fp;

__device__ __forceinline__ __hip_bfloat16 f2b(float v) { return __float2bfloat16(v); }
__device__ __forceinline__ unsigned bfbits(float v) {
    union { __hip_bfloat16 h; unsigned short s; } u; u.h = f2b(v); return (unsigned)u.s;
}

// order-preserving float<->uint key for atomicMax/Min over signed floats
__device__ __forceinline__ unsigned fkey(float f) {
    unsigned u = __float_as_uint(f);
    return u ^ ((u & 0x80000000u) ? 0xFFFFFFFFu : 0x80000000u);
}
__device__ __forceinline__ float funkey(unsigned k) {
    unsigned u = (k & 0x80000000u) ? (k ^ 0x80000000u) : ~k;
    return __uint_as_float(u);
}

union U8 { bf16x8 v; __hip_bfloat16 e[8]; unsigned u[4]; };

static __device__ __forceinline__ f32x4 mfma16(bf16x8 a, bf16x8 b, f32x4 c) {
    return __builtin_amdgcn_mfma_f32_16x16x32_bf16(a, b, c, 0, 0, 0);
}

// ---------------- K0: weight conversion / packing ---------------------------
// W2b: 8192 bf16 [ch2][64]; W3b: 32768 bf16 [ch3][128]; W1p: 64 x {w0,w1,w2,b1} bf16
__global__ void k_prep(fp W1, fp b1, fp W2, fp W3,
                       __hip_bfloat16* __restrict__ W2b,
                       __hip_bfloat16* __restrict__ W3b,
                       unsigned* __restrict__ W1p /* as uint pairs */)
{
    int i = blockIdx.x * blockDim.x + threadIdx.x;
    if (i < 8192) W2b[i] = f2b(W2[i]);
    const int j = i - 8192;
    if (j >= 0 && j < 32768) W3b[j] = f2b(W3[j]);
    const int c = i - 40960;
    if (c >= 0 && c < 64) {
        unsigned lo = bfbits(W1[3*c+0]) | (bfbits(W1[3*c+1]) << 16);
        unsigned hi = bfbits(W1[3*c+2]) | (bfbits(b1[c]) << 16);
        W1p[c*2+0] = lo; W1p[c*2+1] = hi;
    }
}

// ---------------- K1: second-order moments of pcd (analytic BN1 stats) ------
__launch_bounds__(256)
__global__ void k_moments(fp pcd, float* __restrict__ mom)
{
    float s[9];
#pragma unroll
    for (int i = 0; i < 9; ++i) s[i] = 0.f;
    const int stride = gridDim.x * blockDim.x;
    for (int p = blockIdx.x * blockDim.x + threadIdx.x; p < NPTS; p += stride) {
        const float x = pcd[3*p+0], y = pcd[3*p+1], z = pcd[3*p+2];
        s[0] += x; s[1] += y; s[2] += z;
        s[3] = fmaf(x, x, s[3]); s[4] = fmaf(x, y, s[4]); s[5] = fmaf(x, z, s[5]);
        s[6] = fmaf(y, y, s[6]); s[7] = fmaf(y, z, s[7]); s[8] = fmaf(z, z, s[8]);
    }
#pragma unroll
    for (int off = 1; off < 64; off <<= 1) {
#pragma unroll
        for (int i = 0; i < 9; ++i) s[i] += __shfl_xor(s[i], off);
    }
    __shared__ float red[4][9];
    const int lane = threadIdx.x & 63, wv = threadIdx.x >> 6;
    if (lane == 0) {
#pragma unroll
        for (int i = 0; i < 9; ++i) red[wv][i] = s[i];
    }
    __syncthreads();
    if (threadIdx.x < 9) {
        const int i = threadIdx.x;
        atomicAdd(&mom[i], red[0][i] + red[1][i] + red[2][i] + red[3][i]);
    }
}

// ---------------- K2: analytic BN1 scale/shift ------------------------------
__global__ void k_fin1(const float* __restrict__ mom, fp W1, fp b1, fp g1, fp be1,
                       float* __restrict__ s1, float* __restrict__ t1)
{
    const int c = threadIdx.x;  // 64 threads
    const float inv = 1.f / (float)NPTS;
    const float m0 = mom[0]*inv, m1 = mom[1]*inv, m2 = mom[2]*inv;
    const float c00 = mom[3]*inv - m0*m0, c01 = mom[4]*inv - m0*m1, c02 = mom[5]*inv - m0*m2;
    const float c11 = mom[6]*inv - m1*m1, c12 = mom[7]*inv - m1*m2, c22 = mom[8]*inv - m2*m2;
    const float w0 = W1[c*3+0], w1 = W1[c*3+1], w2 = W1[c*3+2];
    const float mu = w0*m0 + w1*m1 + w2*m2 + b1[c];
    float var = w0*w0*c00 + w1*w1*c11 + w2*w2*c22 + 2.f*(w0*w1*c01 + w0*w2*c02 + w1*w2*c12);
    var = fmaxf(var, 0.f);
    const float sc = g1[c] * rsqrtf(var + 1e-5f);
    s1[c] = sc;
    t1[c] = be1[c] - mu*sc;
}

// ---------------- Pass 1: L1 + L2, y2 raw stats (weight-stationary) ---------
// 2048 blocks x 256 thr. Block = 32 per batch, 4 iters x 64 points.
__launch_bounds__(256, 2)
__global__ void k_pass1(fp pcd, const unsigned* __restrict__ W1p,
                        const float* __restrict__ s1, const float* __restrict__ t1,
                        const __hip_bfloat16* __restrict__ W2b,
                        float* __restrict__ st2s, float* __restrict__ st2q)
{
    __shared__ __hip_bfloat16 x1s[64*72];   // stride 72 (144B rows -> 2-way, free)
    const int tid = threadIdx.x, wv = tid >> 6, lane = tid & 63;
    const int m = lane & 15, q = lane >> 4;
    const int batch = blockIdx.x >> 5, sub = blockIdx.x & 31;

    // W1 B-frags (k=0..3 rows: w0,w1,w2,b1) -- q==0 lanes only
    bf16x8 wb1[4];
#pragma unroll
    for (int nt = 0; nt < 4; ++nt) {
        U8 w; w.u[0] = w.u[1] = w.u[2] = w.u[3] = 0;
        if (q == 0) { w.u[0] = W1p[(nt*16+m)*2]; w.u[1] = W1p[(nt*16+m)*2+1]; }
        wb1[nt] = w.v;
    }
    float s1v[4], t1v[4];
#pragma unroll
    for (int nt = 0; nt < 4; ++nt) { s1v[nt] = s1[nt*16+m]; t1v[nt] = t1[nt*16+m]; }

    // W2 B-frags in registers (16 x bf16x8 = 64 VGPRs), rows 0..127 of W2
    bf16x8 wb2[8][2];
#pragma unroll
    for (int nt = 0; nt < 8; ++nt) {
#pragma unroll
        for (int kk = 0; kk < 2; ++kk)
            wb2[nt][kk] = *(const bf16x8*)(W2b + (nt*16+m)*64 + kk*32 + q*8);
    }

    float s_acc[8], q_acc[8];
#pragma unroll
    for (int nt = 0; nt < 8; ++nt) { s_acc[nt] = 0.f; q_acc[nt] = 0.f; }

    const int rowA = (wv*16 + m) * 72;

    for (int it = 0; it < 4; ++it) {
        const int p0 = batch*8192 + sub*256 + it*64 + wv*16;
        const float* pp = pcd + (size_t)(p0 + m) * 3;
        const float cx = pp[0], cy = pp[1], cz = pp[2];
        U8 a1; a1.u[0] = a1.u[1] = a1.u[2] = a1.u[3] = 0;
        if (q == 0) {
            a1.u[0] = bfbits(cx) | (bfbits(cy) << 16);
            a1.u[1] = bfbits(cz) | (bfbits(1.f) << 16);
        }
        // L1 via MFMA, BN1+relu, pack channel pairs, store to LDS (A-layout rows)
#pragma unroll
        for (int nt = 0; nt < 4; ++nt) {
            f32x4 c1 = mfma16(a1.v, wb1[nt], (f32x4){0.f,0.f,0.f,0.f});
#pragma unroll
            for (int r = 0; r < 4; ++r) {
                const float v = fmaxf(fmaf(c1[r], s1v[nt], t1v[nt]), 0.f);
                const unsigned own = bfbits(v);
                const unsigned oth = (unsigned)__shfl_xor((int)own, 1);
                if ((m & 1) == 0) {
                    const int row = wv*16 + q*4 + r;
                    *(unsigned*)&x1s[row*72 + nt*16 + m] = own | (oth << 16);
                }
            }
        }
        // L2: A-frags from own rows (wave-local, in-order DS pipe), 16 MFMA
        const bf16x8 a2k0 = *(const bf16x8*)&x1s[rowA + 0  + q*8];
        const bf16x8 a2k1 = *(const bf16x8*)&x1s[rowA + 32 + q*8];
#pragma unroll
        for (int nt = 0; nt < 8; ++nt) {
            f32x4 c = mfma16(a2k0, wb2[nt][0], (f32x4){0.f,0.f,0.f,0.f});
            c = mfma16(a2k1, wb2[nt][1], c);
            s_acc[nt] += (c[0] + c[1]) + (c[2] + c[3]);
            q_acc[nt] = fmaf(c[0],c[0], fmaf(c[1],c[1], fmaf(c[2],c[2], fmaf(c[3],c[3], q_acc[nt]))));
        }
    }
    // reduce over q (rows), then cross-wave via LDS, then one atomic set
#pragma unroll
    for (int nt = 0; nt < 8; ++nt) {
        s_acc[nt] += __shfl_xor(s_acc[nt], 16); q_acc[nt] += __shfl_xor(q_acc[nt], 16);
        s_acc[nt] += __shfl_xor(s_acc[nt], 32); q_acc[nt] += __shfl_xor(q_acc[nt], 32);
    }
    __syncthreads();
    float* red = (float*)x1s;
    if (q == 0) {
#pragma unroll
        for (int nt = 0; nt < 8; ++nt) {
            red[wv*128 + nt*16 + m] = s_acc[nt];
            red[512 + wv*128 + nt*16 + m] = q_acc[nt];
        }
    }
    __syncthreads();
    if (tid < 128) {
        float s = 0.f, ss = 0.f;
#pragma unroll
        for (int w4 = 0; w4 < 4; ++w4) { s += red[w4*128 + tid]; ss += red[512 + w4*128 + tid]; }
        const int slot = blockIdx.x & 255;
        atomicAdd(&st2s[slot*128 + tid], s);
        atomicAdd(&st2q[slot*128 + tid], ss);
    }
}

// ---------------- K4: finalize BN2 (stats are raw, bias cancels) ------------
__global__ void k_fin2(const float* __restrict__ sum, const float* __restrict__ sq,
                       fp g, fp be, float* __restrict__ sOut, float* __restrict__ tOut)
{
    const int ch = threadIdx.x;  // 128
    float s = 0.f, ss = 0.f;
    for (int slot = 0; slot < 256; ++slot) { s += sum[slot*128 + ch]; ss += sq[slot*128 + ch]; }
    const float inv = 1.f / (float)NPTS;
    const float mu = s * inv;                       // raw mean (b2 cancels in BN)
    const float var = fmaxf(ss * inv - mu*mu, 0.f);
    const float sc = g[ch] * rsqrtf(var + 1e-5f);
    sOut[ch] = sc;
    tOut[ch] = be[ch] - mu*sc;
}

// ---------------- Pass 2: L1+L2+BN2+L3, y3 raw stats + min/max --------------
// Wave w holds W3 channels [w*64, w*64+64) in registers (N-split).
__launch_bounds__(256, 2)
__global__ void k_pass2(fp pcd, const unsigned* __restrict__ W1p,
                        const float* __restrict__ s1, const float* __restrict__ t1,
                        const __hip_bfloat16* __restrict__ W2b,
                        const float* __restrict__ s2, const float* __restrict__ t2,
                        const __hip_bfloat16* __restrict__ W3b,
                        float* __restrict__ st3s, float* __restrict__ st3q,
                        unsigned* __restrict__ maxk, unsigned* __restrict__ mink)
{
    __shared__ __hip_bfloat16 x1s[64*72];     // stride 72
    __shared__ __hip_bfloat16 x2s[64*136];    // stride 136 (2-way, free)
    __shared__ __hip_bfloat16 w2s[128*72];    // W2 staged: ALL 128 rows, stride 72
    const int tid = threadIdx.x, wv = tid >> 6, lane = tid & 63;
    const int m = lane & 15, q = lane >> 4;
    const int batch = blockIdx.x >> 5, sub = blockIdx.x & 31;

    // stage W2 -> LDS: 128 rows x 64 cols; each thread copies 32 contiguous elems
    {
        const int row = tid >> 1, half = tid & 1;   // rows 0..127
#pragma unroll
        for (int jj = 0; jj < 2; ++jj) {
            const bf16x8 wa = *(const bf16x8*)(W2b + row*64 + half*32 + jj*16);
            const bf16x8 wb = *(const bf16x8*)(W2b + row*64 + half*32 + jj*16 + 8);
            *(bf16x8*)&w2s[row*72 + half*32 + jj*16]     = wa;
            *(bf16x8*)&w2s[row*72 + half*32 + jj*16 + 8] = wb;
        }
    }

    bf16x8 wb1[4];
#pragma unroll
    for (int nt = 0; nt < 4; ++nt) {
        U8 w; w.u[0] = w.u[1] = w.u[2] = w.u[3] = 0;
        if (q == 0) { w.u[0] = W1p[(nt*16+m)*2]; w.u[1] = W1p[(nt*16+m)*2+1]; }
        wb1[nt] = w.v;
    }
    float s1v[4], t1v[4];
#pragma unroll
    for (int nt = 0; nt < 4; ++nt) { s1v[nt] = s1[nt*16+m]; t1v[nt] = t1[nt*16+m]; }
    float s2v[8], t2v[8];
#pragma unroll
    for (int nt = 0; nt < 8; ++nt) { s2v[nt] = s2[nt*16+m]; t2v[nt] = t2[nt*16+m]; }

    // W3 slice in registers: 16 x bf16x8 = 64 VGPRs
    bf16x8 wb3[4][4];
#pragma unroll
    for (int nt = 0; nt < 4; ++nt) {
        const int ch3 = wv*64 + nt*16 + m;
#pragma unroll
        for (int ks = 0; ks < 4; ++ks)
            wb3[nt][ks] = *(const bf16x8*)(W3b + ch3*128 + ks*32 + q*8);
    }

    float s3[4], q3[4], mx3[4], mn3[4];
#pragma unroll
    for (int nt = 0; nt < 4; ++nt) { s3[nt]=0.f; q3[nt]=0.f; mx3[nt]=-3.4e38f; mn3[nt]=3.4e38f; }

    const int rowA = (wv*16 + m) * 72;
    __syncthreads();   // w2s staged

    for (int it = 0; it < 4; ++it) {
        asm volatile("" ::: "memory");   // keep per-iter LDS reads inside the loop
        const int p0 = batch*8192 + sub*256 + it*64 + wv*16;
        const float* pp = pcd + (size_t)(p0 + m) * 3;
        const float cx = pp[0], cy = pp[1], cz = pp[2];
        U8 a1; a1.u[0] = a1.u[1] = a1.u[2] = a1.u[3] = 0;
        if (q == 0) {
            a1.u[0] = bfbits(cx) | (bfbits(cy) << 16);
            a1.u[1] = bfbits(cz) | (bfbits(1.f) << 16);
        }
#pragma unroll
        for (int nt = 0; nt < 4; ++nt) {
            f32x4 c1 = mfma16(a1.v, wb1[nt], (f32x4){0.f,0.f,0.f,0.f});
#pragma unroll
            for (int r = 0; r < 4; ++r) {
                const float v = fmaxf(fmaf(c1[r], s1v[nt], t1v[nt]), 0.f);
                const unsigned own = bfbits(v);
                const unsigned oth = (unsigned)__shfl_xor((int)own, 1);
                if ((m & 1) == 0) {
                    const int row = wv*16 + q*4 + r;
                    *(unsigned*)&x1s[row*72 + nt*16 + m] = own | (oth << 16);
                }
            }
        }
        // L2 from LDS-staged W2, BN2+relu -> x2s
        const bf16x8 a2k0 = *(const bf16x8*)&x1s[rowA + 0  + q*8];
        const bf16x8 a2k1 = *(const bf16x8*)&x1s[rowA + 32 + q*8];
#pragma unroll
        for (int nt = 0; nt < 8; ++nt) {
            const bf16x8 wb20 = *(const bf16x8*)&w2s[(nt*16+m)*72 + 0  + q*8];
            const bf16x8 wb21 = *(const bf16x8*)&w2s[(nt*16+m)*72 + 32 + q*8];
            f32x4 c = mfma16(a2k0, wb20, (f32x4){0.f,0.f,0.f,0.f});
            c = mfma16(a2k1, wb21, c);
#pragma unroll
            for (int r = 0; r < 4; ++r) {
                const float v = fmaxf(fmaf(c[r], s2v[nt], t2v[nt]), 0.f);
                const unsigned own = bfbits(v);
                const unsigned oth = (unsigned)__shfl_xor((int)own, 1);
                if ((m & 1) == 0) {
                    const int row = wv*16 + q*4 + r;
                    *(unsigned*)&x2s[row*136 + nt*16 + m] = own | (oth << 16);
                }
            }
        }
        __syncthreads();
        // L3: all 64 points through this wave's W3 slice; raw stats in regs
#pragma unroll
        for (int ms = 0; ms < 4; ++ms) {
            const int rowM = (ms*16 + m) * 136;
            bf16x8 a3[4];
#pragma unroll
            for (int ks = 0; ks < 4; ++ks)
                a3[ks] = *(const bf16x8*)&x2s[rowM + ks*32 + q*8];
#pragma unroll
            for (int nt = 0; nt < 4; ++nt) {
                f32x4 c = mfma16(a3[0], wb3[nt][0], (f32x4){0.f,0.f,0.f,0.f});
                c = mfma16(a3[1], wb3[nt][1], c);
                c = mfma16(a3[2], wb3[nt][2], c);
                c = mfma16(a3[3], wb3[nt][3], c);
                s3[nt] += (c[0] + c[1]) + (c[2] + c[3]);
                q3[nt] = fmaf(c[0],c[0], fmaf(c[1],c[1], fmaf(c[2],c[2], fmaf(c[3],c[3], q3[nt]))));
                mx3[nt] = fmaxf(fmaxf(c[0], c[1]), fmaxf(fmaxf(c[2], c[3]), mx3[nt]));
                mn3[nt] = fminf(fminf(c[0], c[1]), fminf(fminf(c[2], c[3]), mn3[nt]));
            }
        }
        __syncthreads();   // protect x2s before next iteration's writes
    }
    // reduce over q, then one atomic set per block
#pragma unroll
    for (int nt = 0; nt < 4; ++nt) {
        s3[nt] += __shfl_xor(s3[nt], 16);  q3[nt] += __shfl_xor(q3[nt], 16);
        mx3[nt] = fmaxf(mx3[nt], __shfl_xor(mx3[nt], 16));
        mn3[nt] = fminf(mn3[nt], __shfl_xor(mn3[nt], 16));
        s3[nt] += __shfl_xor(s3[nt], 32);  q3[nt] += __shfl_xor(q3[nt], 32);
        mx3[nt] = fmaxf(mx3[nt], __shfl_xor(mx3[nt], 32));
        mn3[nt] = fminf(mn3[nt], __shfl_xor(mn3[nt], 32));
    }
    if (q == 0) {
        const int slot = blockIdx.x & 255;
#pragma unroll
        for (int nt = 0; nt < 4; ++nt) {
            const int ch3 = wv*64 + nt*16 + m;
            atomicAdd(&st3s[slot*256 + ch3], s3[nt]);
            atomicAdd(&st3q[slot*256 + ch3], q3[nt]);
            atomicMax(&maxk[batch*256 + ch3], fkey(mx3[nt]));
            atomicMin(&mink[batch*256 + ch3], fkey(mn3[nt]));
        }
    }
}

// ---------------- K6: finalize BN3 + fold BN3/relu into stored min/max ------
__global__ void k_fin3(const float* __restrict__ sum, const float* __restrict__ sq,
                       fp g, fp be, const unsigned* __restrict__ maxk,
                       const unsigned* __restrict__ mink, float* __restrict__ pre)
{
    const int ch = threadIdx.x;  // 256
    float s = 0.f, ss = 0.f;
    for (int slot = 0; slot < 256; ++slot) { s += sum[slot*256 + ch]; ss += sq[slot*256 + ch]; }
    const float inv = 1.f / (float)NPTS;
    const float mu = s * inv;                       // raw mean (b3 cancels in BN)
    const float var = fmaxf(ss * inv - mu*mu, 0.f);
    const float sc = g[ch] * rsqrtf(var + 1e-5f);
    const float sh = be[ch] - mu*sc;
    for (int b = 0; b < NBATCH; ++b) {
        const float fmx = funkey(maxk[b*256 + ch]);
        const float fmn = funkey(mink[b*256 + ch]);
        const float pick = (sc >= 0.f) ? fmx : fmn;   // max_n relu(s*y+t) = relu(s*ext(y)+t)
        pre[b*256 + ch] = fmaxf(fmaf(pick, sc, sh), 0.f);
    }
}

// ---------------- K8: heads + QP (1 block / batch) --------------------------
__launch_bounds__(128)
__global__ void k_head(const float* __restrict__ pre,
                       fp Wfc, fp bfc, fp Wc1, fp bc1, fp Wc2, fp bc2,
                       fp Wp1, fp bp1, fp Wp2, fp bp2,
                       float* __restrict__ out)
{
    __shared__ float pf[256], ft[128], hcs[128], hps[64], ocs[48], nrm[36], hS[12], pp[8];
    const int bb = blockIdx.x, tid = threadIdx.x;
    pf[tid] = pre[bb*256 + tid];
    pf[tid+128] = pre[bb*256 + 128 + tid];
    __syncthreads();
    {
        float a = bfc[tid];
        const float* wr = Wfc + tid*256;
        for (int k = 0; k < 256; ++k) a = fmaf(pf[k], wr[k], a);
        ft[tid] = a;
    }
    __syncthreads();
    {
        float a = bc1[tid];
        const float* wr = Wc1 + tid*128;
        for (int k = 0; k < 128; ++k) a = fmaf(ft[k], wr[k], a);
        hcs[tid] = fmaxf(a, 0.f);
    }
    if (tid < 64) {
        float a = bp1[tid];
        const float* wr = Wp1 + tid*128;
        for (int k = 0; k < 128; ++k) a = fmaf(ft[k], wr[k], a);
        hps[tid] = fmaxf(a, 0.f);
    }
    __syncthreads();
    if (tid < 48) {
        float a = bc2[tid];
        const float* wr = Wc2 + tid*128;
        for (int k = 0; k < 128; ++k) a = fmaf(hcs[k], wr[k], a);
        ocs[tid] = a;
    }
    if (tid < 7) {
        float a = bp2[tid];
        const float* wr = Wp2 + tid*64;
        for (int k = 0; k < 64; ++k) a = fmaf(hps[k], wr[k], a);
        const float sc = (tid < 3) ? 0.1f : ((tid < 6) ? 1.57f : 0.05f);
        pp[tid] = tanhf(a) * sc;
    }
    __syncthreads();
    if (tid < 12) {
        float nx = ocs[tid*4+0], ny = ocs[tid*4+1], nz = ocs[tid*4+2];
        const float nn = fmaxf(sqrtf(nx*nx + ny*ny + nz*nz), 1e-12f);
        const float inv = 1.f / nn;
        nx *= inv; ny *= inv; nz *= inv;
        nrm[tid*3+0] = nx; nrm[tid*3+1] = ny; nrm[tid*3+2] = nz;
        const float xx = ocs[tid*4+3];
        hS[tid] = ((xx > 20.f) ? xx : log1pf(expf(xx))) + 0.005f;
    }
    __syncthreads();

    // QP: 500 projected-gradient iterations; lanes 0..11 own lam_c.
    const int lane = tid & 63;
    const int c = (lane < 12) ? lane : 11;
    const float n0 = nrm[c*3+0], n1 = nrm[c*3+1], n2 = nrm[c*3+2];
    float Mrow[12];
    float trace = 0.f;
#pragma unroll
    for (int d = 0; d < 12; ++d) {
        const float d0 = nrm[d*3+0], d1 = nrm[d*3+1], d2 = nrm[d*3+2];
        Mrow[d] = n0*d0 + n1*d1 + n2*d2 + ((d == lane) ? 5e-4f : 0.f);
        trace += d0*d0 + d1*d1 + d2*d2;
    }
    const float alpha = 1.f / (trace + 12.f*5e-4f);
    const float qc = n0*pp[0] + n1*pp[1] + n2*pp[2] - hS[c];
    float lam = 0.f;
    for (int it = 0; it < 500; ++it) {
        const float l0 = __shfl(lam, 0),  l1 = __shfl(lam, 1),  l2 = __shfl(lam, 2);
        const float l3 = __shfl(lam, 3),  l4 = __shfl(lam, 4),  l5 = __shfl(lam, 5);
        const float l6 = __shfl(lam, 6),  l7 = __shfl(lam, 7),  l8 = __shfl(lam, 8);
        const float l9 = __shfl(lam, 9),  l10 = __shfl(lam, 10), l11 = __shfl(lam, 11);
        const float g0 = fmaf(Mrow[0], l0, fmaf(Mrow[3], l3, fmaf(Mrow[6], l6, Mrow[9]*l9)));
        const float g1 = fmaf(Mrow[1], l1, fmaf(Mrow[4], l4, fmaf(Mrow[7], l7, Mrow[10]*l10)));
        const float g2 = fmaf(Mrow[2], l2, fmaf(Mrow[5], l5, fmaf(Mrow[8], l8, Mrow[11]*l11)));
        lam = fmaxf(fmaf(-alpha, g0 + g1 + g2 - qc, lam), 0.f);
    }
    float v0 = (lane < 12) ? n0*lam : 0.f;
    float v1 = (lane < 12) ? n1*lam : 0.f;
    float v2 = (lane < 12) ? n2*lam : 0.f;
#pragma unroll
    for (int off = 1; off <= 8; off <<= 1) {
        v0 += __shfl_xor(v0, off);
        v1 += __shfl_xor(v1, off);
        v2 += __shfl_xor(v2, off);
    }
    // outputs: delta_norm(64x7) | normals(64x12x3) | h(64x12) | p_pred(64x7)
    if (tid < 7) {
        float z;
        if (tid == 0) z = pp[0] - v0;
        else if (tid == 1) z = pp[1] - v1;
        else if (tid == 2) z = pp[2] - v2;
        else z = pp[tid];
        out[bb*7 + tid] = z;
    }
    if (tid < 36) out[448 + bb*36 + tid] = nrm[tid];
    if (tid < 12) out[2752 + bb*12 + tid] = hS[tid];
    if (tid < 7)  out[3520 + bb*7 + tid] = pp[tid];
}

// ---------------- host ------------------------------------------------------
extern "C" void kernel_launch(void* const* d_in, const int* in_sizes, int n_in,
                              void* d_out, int out_size, void* d_ws, size_t ws_size,
                              hipStream_t stream) {
    fp pcd = (fp)d_in[0];
    fp W1 = (fp)d_in[1],  b1 = (fp)d_in[2],  g1 = (fp)d_in[3],  be1 = (fp)d_in[4];
    fp W2 = (fp)d_in[5],  b2 = (fp)d_in[6],  g2 = (fp)d_in[7],  be2 = (fp)d_in[8];
    fp W3 = (fp)d_in[9],  b3 = (fp)d_in[10], g3 = (fp)d_in[11], be3 = (fp)d_in[12];
    fp Wfc = (fp)d_in[13], bfc = (fp)d_in[14];
    fp Wc1 = (fp)d_in[15], bc1 = (fp)d_in[16];
    fp Wc2 = (fp)d_in[17], bc2 = (fp)d_in[18];
    fp Wp1 = (fp)d_in[19], bp1 = (fp)d_in[20];
    fp Wp2 = (fp)d_in[21], bp2 = (fp)d_in[22];
    (void)b2; (void)b3;   // pre-BN biases cancel analytically in BN

    float* ws = (float*)d_ws;
    float* mom  = ws + 0;          // 16
    float* s1   = ws + 16;         // 64
    float* t1   = ws + 80;         // 64
    float* s2   = ws + 144;        // 128
    float* t2   = ws + 272;        // 128
    float* pre  = ws + 400;        // 64*256 = 16384
    float* st2s = ws + 16784;      // 256*128 = 32768
    float* st2q = ws + 49552;      // 32768
    float* st3s = ws + 82320;      // 256*256 = 65536
    float* st3q = ws + 147856;     // 65536
    unsigned* maxk = (unsigned*)(ws + 213392);  // 64*256
    unsigned* mink = (unsigned*)(ws + 229776);  // 64*256
    __hip_bfloat16* W2b = (__hip_bfloat16*)(ws + 246160);  // 8192 bf16
    __hip_bfloat16* W3b = (__hip_bfloat16*)(ws + 250256);  // 32768 bf16
    unsigned* W1p = (unsigned*)(ws + 266640);              // 64*2 uint
    if (ws_size < (size_t)266768 * 4) return;

    hipMemsetAsync(d_ws, 0, (size_t)229776 * 4, stream);           // stats + maxk
    hipMemsetAsync((void*)mink, 0xFF, (size_t)16384 * 4, stream);  // mink

    k_prep<<<161, 256, 0, stream>>>(W1, b1, W2, W3, W2b, W3b, W1p);
    k_moments<<<256, 256, 0, stream>>>(pcd, mom);
    k_fin1<<<1, 64, 0, stream>>>(mom, W1, b1, g1, be1, s1, t1);
    k_pass1<<<2048, 256, 0, stream>>>(pcd, W1p, s1, t1, W2b, st2s, st2q);
    k_fin2<<<1, 128, 0, stream>>>(st2s, st2q, g2, be2, s2, t2);
    k_pass2<<<2048, 256, 0, stream>>>(pcd, W1p, s1, t1, W2b, s2, t2, W3b,
                                      st3s, st3q, maxk, mink);
    k_fin3<<<1, 256, 0, stream>>>(st3s, st3q, g3, be3, maxk, mink, pre);
    k_head<<<64, 128, 0, stream>>>(pre, Wfc, bfc, Wc1, bc1, Wc2, bc2,
                                   Wp1, bp1, Wp2, bp2, (float*)d_out);
}

// Round 6
// 319.085 us; speedup vs baseline: 2.1406x; 1.0297x over previous
//
#include <hip/hip_runtime.h>
#include <hip/hip_bf16.h>

#define NPTS 524288   // 64 * 8192
#define NBATCH 64

typedef __attribute__((ext_vector_type(8))) short bf16x8;
typedef __attribute__((ext_vector_type(4))) float f32x4;
typedef const float* __restrict__ fp;

__device__ __forceinline__ __hip_bfloat16 f2b(float v) { return __float2bfloat16(v); }
__device__ __forceinline__ unsigned bfbits(float v) {
    union { __hip_bfloat16 h; unsigned short s; } u; u.h = f2b(v); return (unsigned)u.s;
}
__device__ __forceinline__ unsigned pk2(float a, float b) {
    return bfbits(a) | (bfbits(b) << 16);
}

// order-preserving float<->uint key for atomicMax/Min over signed floats
__device__ __forceinline__ unsigned fkey(float f) {
    unsigned u = __float_as_uint(f);
    return u ^ ((u & 0x80000000u) ? 0xFFFFFFFFu : 0x80000000u);
}
__device__ __forceinline__ float funkey(unsigned k) {
    unsigned u = (k & 0x80000000u) ? (k ^ 0x80000000u) : ~k;
    return __uint_as_float(u);
}

union U8 { bf16x8 v; __hip_bfloat16 e[8]; unsigned u[4]; };

static __device__ __forceinline__ f32x4 mfma16(bf16x8 a, bf16x8 b, f32x4 c) {
    return __builtin_amdgcn_mfma_f32_16x16x32_bf16(a, b, c, 0, 0, 0);
}

// ---------------- K0: W2/W3 -> bf16 (no deps, runs first) -------------------
__global__ void k_prep(fp W2, fp W3, __hip_bfloat16* __restrict__ W2b,
                       __hip_bfloat16* __restrict__ W3b)
{
    int i = blockIdx.x * blockDim.x + threadIdx.x;
    if (i < 8192) W2b[i] = f2b(W2[i]);
    const int j = i - 8192;
    if (j >= 0 && j < 32768) W3b[j] = f2b(W3[j]);
}

// ---------------- K1: second-order moments of pcd (analytic BN1 stats) ------
__launch_bounds__(256)
__global__ void k_moments(fp pcd, float* __restrict__ mom)
{
    float s[9];
#pragma unroll
    for (int i = 0; i < 9; ++i) s[i] = 0.f;
    const int stride = gridDim.x * blockDim.x;
    for (int p = blockIdx.x * blockDim.x + threadIdx.x; p < NPTS; p += stride) {
        const float x = pcd[3*p+0], y = pcd[3*p+1], z = pcd[3*p+2];
        s[0] += x; s[1] += y; s[2] += z;
        s[3] = fmaf(x, x, s[3]); s[4] = fmaf(x, y, s[4]); s[5] = fmaf(x, z, s[5]);
        s[6] = fmaf(y, y, s[6]); s[7] = fmaf(y, z, s[7]); s[8] = fmaf(z, z, s[8]);
    }
#pragma unroll
    for (int off = 1; off < 64; off <<= 1) {
#pragma unroll
        for (int i = 0; i < 9; ++i) s[i] += __shfl_xor(s[i], off);
    }
    __shared__ float red[4][9];
    const int lane = threadIdx.x & 63, wv = threadIdx.x >> 6;
    if (lane == 0) {
#pragma unroll
        for (int i = 0; i < 9; ++i) red[wv][i] = s[i];
    }
    __syncthreads();
    if (threadIdx.x < 9) {
        const int i = threadIdx.x;
        atomicAdd(&mom[i], red[0][i] + red[1][i] + red[2][i] + red[3][i]);
    }
}

// ---------------- K2: analytic BN1 folded straight into W1 ------------------
// W1p[c] = {s1*w0, s1*w1, s1*w2, s1*b1 + t1} as 2 packed bf16 uints.
__global__ void k_fin1(const float* __restrict__ mom, fp W1, fp b1, fp g1, fp be1,
                       unsigned* __restrict__ W1p)
{
    const int c = threadIdx.x;  // 64 threads
    const float inv = 1.f / (float)NPTS;
    const float m0 = mom[0]*inv, m1 = mom[1]*inv, m2 = mom[2]*inv;
    const float c00 = mom[3]*inv - m0*m0, c01 = mom[4]*inv - m0*m1, c02 = mom[5]*inv - m0*m2;
    const float c11 = mom[6]*inv - m1*m1, c12 = mom[7]*inv - m1*m2, c22 = mom[8]*inv - m2*m2;
    const float w0 = W1[c*3+0], w1 = W1[c*3+1], w2 = W1[c*3+2];
    const float mu = w0*m0 + w1*m1 + w2*m2 + b1[c];
    float var = w0*w0*c00 + w1*w1*c11 + w2*w2*c22 + 2.f*(w0*w1*c01 + w0*w2*c02 + w1*w2*c12);
    var = fmaxf(var, 0.f);
    const float sc = g1[c] * rsqrtf(var + 1e-5f);
    const float sh = be1[c] - mu*sc;
    W1p[c*2+0] = pk2(w0*sc, w1*sc);
    W1p[c*2+1] = pk2(w2*sc, b1[c]*sc + sh);
}

// L1 (A=W1' folded, B=pcd) + in-register redistribution to L2 A-fragments.
// u1s[nt][t] = bf16 pair of chs (nt*16+q*4+2t, +1) of pt m (C/D layout).
// Dest lane (m,q) needs ch pair base ks*32+q*8+2*t2 of pt m, which lives in
// source lane (m, q'=(q&1)*2+(t2>>1)), register u1s[2ks+(q>>1)][t2&1].
// The register index depends on the DEST's q>>1 while __shfl evaluates in the
// SOURCE lane (r5 bug) -> shuffle both candidates, select after by dest q.
#define L1_AND_REDIST(a2f)                                                      \
    {                                                                           \
        unsigned u1s[4][2];                                                     \
        _Pragma("unroll")                                                       \
        for (int nt = 0; nt < 4; ++nt) {                                        \
            f32x4 c1 = mfma16(wb1[nt], a1.v, (f32x4){0.f,0.f,0.f,0.f});         \
            u1s[nt][0] = pk2(fmaxf(c1[0],0.f), fmaxf(c1[1],0.f));               \
            u1s[nt][1] = pk2(fmaxf(c1[2],0.f), fmaxf(c1[3],0.f));               \
        }                                                                       \
        const int srcBase = m + ((q & 1) ? 32 : 0);                             \
        _Pragma("unroll")                                                       \
        for (int ks = 0; ks < 2; ++ks) {                                        \
            _Pragma("unroll")                                                   \
            for (int t2 = 0; t2 < 4; ++t2) {                                    \
                const int src = srcBase + 16*(t2>>1);                           \
                const unsigned rlo = (unsigned)__shfl((int)u1s[2*ks  ][t2&1], src); \
                const unsigned rhi = (unsigned)__shfl((int)u1s[2*ks+1][t2&1], src); \
                a2f[ks].u[t2] = (q >= 2) ? rhi : rlo;                           \
            }                                                                   \
        }                                                                       \
    }

// ---------------- Pass 1: L1 + L2, y2 raw stats (zero-LDS main loop) --------
// 2048 blocks x 256 thr; block = 32/batch, 4 iters x 64 points.
__launch_bounds__(256, 3)
__global__ void k_pass1(fp pcd, const unsigned* __restrict__ W1p,
                        const __hip_bfloat16* __restrict__ W2b,
                        float* __restrict__ st2s, float* __restrict__ st2q)
{
    __shared__ float red[1024];
    const int tid = threadIdx.x, wv = tid >> 6, lane = tid & 63;
    const int m = lane & 15, q = lane >> 4;
    const int batch = blockIdx.x >> 5, sub = blockIdx.x & 31;

    bf16x8 wb1[4];
#pragma unroll
    for (int nt = 0; nt < 4; ++nt) {
        U8 w; w.u[0] = w.u[1] = w.u[2] = w.u[3] = 0;
        if (q == 0) { w.u[0] = W1p[(nt*16+m)*2]; w.u[1] = W1p[(nt*16+m)*2+1]; }
        wb1[nt] = w.v;
    }
    bf16x8 wb2[8][2];
#pragma unroll
    for (int nt = 0; nt < 8; ++nt) {
#pragma unroll
        for (int kk = 0; kk < 2; ++kk)
            wb2[nt][kk] = *(const bf16x8*)(W2b + (nt*16+m)*64 + kk*32 + q*8);
    }

    float s_acc[8], q_acc[8];
#pragma unroll
    for (int nt = 0; nt < 8; ++nt) { s_acc[nt] = 0.f; q_acc[nt] = 0.f; }

    for (int it = 0; it < 4; ++it) {
        const int p0 = batch*8192 + sub*256 + it*64 + wv*16;
        const float* pp = pcd + (size_t)(p0 + m) * 3;
        const float cx = pp[0], cy = pp[1], cz = pp[2];
        U8 a1; a1.u[0] = a1.u[1] = a1.u[2] = a1.u[3] = 0;
        if (q == 0) { a1.u[0] = pk2(cx, cy); a1.u[1] = pk2(cz, 1.f); }

        U8 a2f[2];
        L1_AND_REDIST(a2f)

#pragma unroll
        for (int nt = 0; nt < 8; ++nt) {
            f32x4 c = mfma16(a2f[0].v, wb2[nt][0], (f32x4){0.f,0.f,0.f,0.f});
            c = mfma16(a2f[1].v, wb2[nt][1], c);
            s_acc[nt] += (c[0] + c[1]) + (c[2] + c[3]);
            q_acc[nt] = fmaf(c[0],c[0], fmaf(c[1],c[1], fmaf(c[2],c[2], fmaf(c[3],c[3], q_acc[nt]))));
        }
    }
#pragma unroll
    for (int nt = 0; nt < 8; ++nt) {
        s_acc[nt] += __shfl_xor(s_acc[nt], 16); q_acc[nt] += __shfl_xor(q_acc[nt], 16);
        s_acc[nt] += __shfl_xor(s_acc[nt], 32); q_acc[nt] += __shfl_xor(q_acc[nt], 32);
    }
    if (q == 0) {
#pragma unroll
        for (int nt = 0; nt < 8; ++nt) {
            red[wv*128 + nt*16 + m] = s_acc[nt];
            red[512 + wv*128 + nt*16 + m] = q_acc[nt];
        }
    }
    __syncthreads();
    if (tid < 128) {
        float s = 0.f, ss = 0.f;
#pragma unroll
        for (int w4 = 0; w4 < 4; ++w4) { s += red[w4*128 + tid]; ss += red[512 + w4*128 + tid]; }
        const int slot = blockIdx.x & 63;
        atomicAdd(&st2s[slot*128 + tid], s);
        atomicAdd(&st2q[slot*128 + tid], ss);
    }
}

// ---------------- K4: finalize BN2 (raw stats; b2 cancels in BN) ------------
__global__ void k_fin2(const float* __restrict__ sum, const float* __restrict__ sq,
                       fp g, fp be, float* __restrict__ sOut, float* __restrict__ tOut)
{
    const int ch = threadIdx.x;  // 128
    float s = 0.f, ss = 0.f;
    for (int slot = 0; slot < 64; ++slot) { s += sum[slot*128 + ch]; ss += sq[slot*128 + ch]; }
    const float inv = 1.f / (float)NPTS;
    const float mu = s * inv;
    const float var = fmaxf(ss * inv - mu*mu, 0.f);
    const float sc = g[ch] * rsqrtf(var + 1e-5f);
    sOut[ch] = sc;
    tOut[ch] = be[ch] - mu*sc;
}

// ---------------- Pass 2: L1+L2+BN2+L3, y3 raw stats + min/max --------------
// Wave w holds W3 channels [w*64, w*64+64) in registers; W2 in registers;
// x2 double-buffered in LDS (1 barrier/iter); x1 never touches LDS.
__launch_bounds__(256, 2)
__global__ void k_pass2(fp pcd, const unsigned* __restrict__ W1p,
                        const __hip_bfloat16* __restrict__ W2b,
                        const float* __restrict__ s2, const float* __restrict__ t2,
                        const __hip_bfloat16* __restrict__ W3b,
                        float* __restrict__ st3s, float* __restrict__ st3q,
                        unsigned* __restrict__ maxk, unsigned* __restrict__ mink)
{
    __shared__ alignas(16) __hip_bfloat16 x2s[2][64*136];   // stride 136 (2-way, free)
    const int tid = threadIdx.x, wv = tid >> 6, lane = tid & 63;
    const int m = lane & 15, q = lane >> 4;
    const int batch = blockIdx.x >> 5, sub = blockIdx.x & 31;

    bf16x8 wb1[4];
#pragma unroll
    for (int nt = 0; nt < 4; ++nt) {
        U8 w; w.u[0] = w.u[1] = w.u[2] = w.u[3] = 0;
        if (q == 0) { w.u[0] = W1p[(nt*16+m)*2]; w.u[1] = W1p[(nt*16+m)*2+1]; }
        wb1[nt] = w.v;
    }
    bf16x8 wb2[8][2];
#pragma unroll
    for (int nt = 0; nt < 8; ++nt) {
#pragma unroll
        for (int kk = 0; kk < 2; ++kk)
            wb2[nt][kk] = *(const bf16x8*)(W2b + (nt*16+m)*64 + kk*32 + q*8);
    }
    float s2v[8], t2v[8];
#pragma unroll
    for (int nt = 0; nt < 8; ++nt) { s2v[nt] = s2[nt*16+m]; t2v[nt] = t2[nt*16+m]; }

    bf16x8 wb3[4][4];
#pragma unroll
    for (int nt = 0; nt < 4; ++nt) {
        const int ch3 = wv*64 + nt*16 + m;
#pragma unroll
        for (int ks = 0; ks < 4; ++ks)
            wb3[nt][ks] = *(const bf16x8*)(W3b + ch3*128 + ks*32 + q*8);
    }

    float s3[4], q3[4], mx3[4], mn3[4];
#pragma unroll
    for (int nt = 0; nt < 4; ++nt) { s3[nt]=0.f; q3[nt]=0.f; mx3[nt]=-3.4e38f; mn3[nt]=3.4e38f; }

    for (int it = 0; it < 4; ++it) {
        __hip_bfloat16* xb = x2s[it & 1];
        const int p0 = batch*8192 + sub*256 + it*64 + wv*16;
        const float* pp = pcd + (size_t)(p0 + m) * 3;
        const float cx = pp[0], cy = pp[1], cz = pp[2];
        U8 a1; a1.u[0] = a1.u[1] = a1.u[2] = a1.u[3] = 0;
        if (q == 0) { a1.u[0] = pk2(cx, cy); a1.u[1] = pk2(cz, 1.f); }

        U8 a2f[2];
        L1_AND_REDIST(a2f)

        // L2 (A=x1 pts, B=W2 chs) + BN2 + relu -> x2 LDS (pt-rows, bf16 pairs)
#pragma unroll
        for (int nt = 0; nt < 8; ++nt) {
            f32x4 c = mfma16(a2f[0].v, wb2[nt][0], (f32x4){0.f,0.f,0.f,0.f});
            c = mfma16(a2f[1].v, wb2[nt][1], c);
#pragma unroll
            for (int r = 0; r < 4; ++r) {
                const float v = fmaxf(fmaf(c[r], s2v[nt], t2v[nt]), 0.f);
                const unsigned own = bfbits(v);
                const unsigned oth = (unsigned)__shfl_xor((int)own, 1);
                if ((m & 1) == 0) {
                    const int row = wv*16 + q*4 + r;
                    *(unsigned*)&xb[row*136 + nt*16 + m] = own | (oth << 16);
                }
            }
        }
        __syncthreads();   // x2[buf] complete (prev-buf reads fenced last iter)
        // L3: all 64 points through this wave's W3 slice
#pragma unroll
        for (int ms = 0; ms < 4; ++ms) {
            const int rowM = (ms*16 + m) * 136;
            bf16x8 a3[4];
#pragma unroll
            for (int ks = 0; ks < 4; ++ks)
                a3[ks] = *(const bf16x8*)&xb[rowM + ks*32 + q*8];
#pragma unroll
            for (int nt = 0; nt < 4; ++nt) {
                f32x4 c = mfma16(a3[0], wb3[nt][0], (f32x4){0.f,0.f,0.f,0.f});
                c = mfma16(a3[1], wb3[nt][1], c);
                c = mfma16(a3[2], wb3[nt][2], c);
                c = mfma16(a3[3], wb3[nt][3], c);
                s3[nt] += (c[0] + c[1]) + (c[2] + c[3]);
                q3[nt] = fmaf(c[0],c[0], fmaf(c[1],c[1], fmaf(c[2],c[2], fmaf(c[3],c[3], q3[nt]))));
                mx3[nt] = fmaxf(fmaxf(c[0], c[1]), fmaxf(fmaxf(c[2], c[3]), mx3[nt]));
                mn3[nt] = fminf(fminf(c[0], c[1]), fminf(fminf(c[2], c[3]), mn3[nt]));
            }
        }
    }
#pragma unroll
    for (int nt = 0; nt < 4; ++nt) {
        s3[nt] += __shfl_xor(s3[nt], 16);  q3[nt] += __shfl_xor(q3[nt], 16);
        mx3[nt] = fmaxf(mx3[nt], __shfl_xor(mx3[nt], 16));
        mn3[nt] = fminf(mn3[nt], __shfl_xor(mn3[nt], 16));
        s3[nt] += __shfl_xor(s3[nt], 32);  q3[nt] += __shfl_xor(q3[nt], 32);
        mx3[nt] = fmaxf(mx3[nt], __shfl_xor(mx3[nt], 32));
        mn3[nt] = fminf(mn3[nt], __shfl_xor(mn3[nt], 32));
    }
    if (q == 0) {
        const int slot = blockIdx.x & 63;
#pragma unroll
        for (int nt = 0; nt < 4; ++nt) {
            const int ch3 = wv*64 + nt*16 + m;
            atomicAdd(&st3s[slot*256 + ch3], s3[nt]);
            atomicAdd(&st3q[slot*256 + ch3], q3[nt]);
            atomicMax(&maxk[batch*256 + ch3], fkey(mx3[nt]));
            atomicMin(&mink[batch*256 + ch3], fkey(mn3[nt]));
        }
    }
}

// ---------------- K8: BN3-fold + heads + QP (1 block / batch) ---------------
__launch_bounds__(128)
__global__ void k_head(const float* __restrict__ st3s, const float* __restrict__ st3q,
                       fp g3, fp be3,
                       const unsigned* __restrict__ maxk, const unsigned* __restrict__ mink,
                       fp Wfc, fp bfc, fp Wc1, fp bc1, fp Wc2, fp bc2,
                       fp Wp1, fp bp1, fp Wp2, fp bp2,
                       float* __restrict__ out)
{
    __shared__ float pf[256], ft[128], hcs[128], hps[64], ocs[48], nrm[36], hS[12], pp[8];
    const int bb = blockIdx.x, tid = threadIdx.x;
    // inline fin3: BN3 stats + fold BN3/relu/maxpool via min/max keys
#pragma unroll
    for (int h = 0; h < 2; ++h) {
        const int ch = tid + h*128;
        float s = 0.f, ss = 0.f;
        for (int slot = 0; slot < 64; ++slot) { s += st3s[slot*256 + ch]; ss += st3q[slot*256 + ch]; }
        const float inv = 1.f / (float)NPTS;
        const float mu = s * inv;
        const float var = fmaxf(ss * inv - mu*mu, 0.f);
        const float sc = g3[ch] * rsqrtf(var + 1e-5f);
        const float sh = be3[ch] - mu*sc;
        const float pick = (sc >= 0.f) ? funkey(maxk[bb*256 + ch]) : funkey(mink[bb*256 + ch]);
        pf[ch] = fmaxf(fmaf(pick, sc, sh), 0.f);
    }
    __syncthreads();
    {
        float a = bfc[tid];
        const float* wr = Wfc + tid*256;
        for (int k = 0; k < 256; ++k) a = fmaf(pf[k], wr[k], a);
        ft[tid] = a;
    }
    __syncthreads();
    {
        float a = bc1[tid];
        const float* wr = Wc1 + tid*128;
        for (int k = 0; k < 128; ++k) a = fmaf(ft[k], wr[k], a);
        hcs[tid] = fmaxf(a, 0.f);
    }
    if (tid < 64) {
        float a = bp1[tid];
        const float* wr = Wp1 + tid*128;
        for (int k = 0; k < 128; ++k) a = fmaf(ft[k], wr[k], a);
        hps[tid] = fmaxf(a, 0.f);
    }
    __syncthreads();
    if (tid < 48) {
        float a = bc2[tid];
        const float* wr = Wc2 + tid*128;
        for (int k = 0; k < 128; ++k) a = fmaf(hcs[k], wr[k], a);
        ocs[tid] = a;
    }
    if (tid < 7) {
        float a = bp2[tid];
        const float* wr = Wp2 + tid*64;
        for (int k = 0; k < 64; ++k) a = fmaf(hps[k], wr[k], a);
        const float sc = (tid < 3) ? 0.1f : ((tid < 6) ? 1.57f : 0.05f);
        pp[tid] = tanhf(a) * sc;
    }
    __syncthreads();
    if (tid < 12) {
        float nx = ocs[tid*4+0], ny = ocs[tid*4+1], nz = ocs[tid*4+2];
        const float nn = fmaxf(sqrtf(nx*nx + ny*ny + nz*nz), 1e-12f);
        const float inv = 1.f / nn;
        nx *= inv; ny *= inv; nz *= inv;
        nrm[tid*3+0] = nx; nrm[tid*3+1] = ny; nrm[tid*3+2] = nz;
        const float xx = ocs[tid*4+3];
        hS[tid] = ((xx > 20.f) ? xx : log1pf(expf(xx))) + 0.005f;
    }
    __syncthreads();

    // QP: 500 projected-gradient iterations; lanes 0..11 own lam_c.
    const int lane = tid & 63;
    const int c = (lane < 12) ? lane : 11;
    const float n0 = nrm[c*3+0], n1 = nrm[c*3+1], n2 = nrm[c*3+2];
    float Mrow[12];
    float trace = 0.f;
#pragma unroll
    for (int d = 0; d < 12; ++d) {
        const float d0 = nrm[d*3+0], d1 = nrm[d*3+1], d2 = nrm[d*3+2];
        Mrow[d] = n0*d0 + n1*d1 + n2*d2 + ((d == lane) ? 5e-4f : 0.f);
        trace += d0*d0 + d1*d1 + d2*d2;
    }
    const float alpha = 1.f / (trace + 12.f*5e-4f);
    const float qc = n0*pp[0] + n1*pp[1] + n2*pp[2] - hS[c];
    float lam = 0.f;
    for (int it = 0; it < 500; ++it) {
        const float l0 = __shfl(lam, 0),  l1 = __shfl(lam, 1),  l2 = __shfl(lam, 2);
        const float l3 = __shfl(lam, 3),  l4 = __shfl(lam, 4),  l5 = __shfl(lam, 5);
        const float l6 = __shfl(lam, 6),  l7 = __shfl(lam, 7),  l8 = __shfl(lam, 8);
        const float l9 = __shfl(lam, 9),  l10 = __shfl(lam, 10), l11 = __shfl(lam, 11);
        const float g0 = fmaf(Mrow[0], l0, fmaf(Mrow[3], l3, fmaf(Mrow[6], l6, Mrow[9]*l9)));
        const float g1 = fmaf(Mrow[1], l1, fmaf(Mrow[4], l4, fmaf(Mrow[7], l7, Mrow[10]*l10)));
        const float g2 = fmaf(Mrow[2], l2, fmaf(Mrow[5], l5, fmaf(Mrow[8], l8, Mrow[11]*l11)));
        lam = fmaxf(fmaf(-alpha, g0 + g1 + g2 - qc, lam), 0.f);
    }
    float v0 = (lane < 12) ? n0*lam : 0.f;
    float v1 = (lane < 12) ? n1*lam : 0.f;
    float v2 = (lane < 12) ? n2*lam : 0.f;
#pragma unroll
    for (int off = 1; off <= 8; off <<= 1) {
        v0 += __shfl_xor(v0, off);
        v1 += __shfl_xor(v1, off);
        v2 += __shfl_xor(v2, off);
    }
    // outputs: delta_norm(64x7) | normals(64x12x3) | h(64x12) | p_pred(64x7)
    if (tid < 7) {
        float z;
        if (tid == 0) z = pp[0] - v0;
        else if (tid == 1) z = pp[1] - v1;
        else if (tid == 2) z = pp[2] - v2;
        else z = pp[tid];
        out[bb*7 + tid] = z;
    }
    if (tid < 36) out[448 + bb*36 + tid] = nrm[tid];
    if (tid < 12) out[2752 + bb*12 + tid] = hS[tid];
    if (tid < 7)  out[3520 + bb*7 + tid] = pp[tid];
}

// ---------------- host ------------------------------------------------------
extern "C" void kernel_launch(void* const* d_in, const int* in_sizes, int n_in,
                              void* d_out, int out_size, void* d_ws, size_t ws_size,
                              hipStream_t stream) {
    fp pcd = (fp)d_in[0];
    fp W1 = (fp)d_in[1],  fp_b1 = (fp)d_in[2],  g1 = (fp)d_in[3],  be1 = (fp)d_in[4];
    fp W2 = (fp)d_in[5],  g2 = (fp)d_in[7],  be2 = (fp)d_in[8];
    fp W3 = (fp)d_in[9],  g3 = (fp)d_in[11], be3 = (fp)d_in[12];
    fp Wfc = (fp)d_in[13], bfc = (fp)d_in[14];
    fp Wc1 = (fp)d_in[15], bc1 = (fp)d_in[16];
    fp Wc2 = (fp)d_in[17], bc2 = (fp)d_in[18];
    fp Wp1 = (fp)d_in[19], bp1 = (fp)d_in[20];
    fp Wp2 = (fp)d_in[21], bp2 = (fp)d_in[22];
    // b2 (d_in[6]) / b3 (d_in[10]) cancel analytically in BN

    float* ws = (float*)d_ws;
    float* mom  = ws + 0;           // 16
    float* s2   = ws + 144;         // 128
    float* t2   = ws + 272;         // 128
    float* st2s = ws + 400;         // 64*128 = 8192
    float* st2q = ws + 8592;        // 8192
    float* st3s = ws + 16784;       // 64*256 = 16384
    float* st3q = ws + 33168;       // 16384
    unsigned* maxk = (unsigned*)(ws + 49552);   // 16384 (0-init ok: keys>0)
    unsigned* mink = (unsigned*)(ws + 65936);   // 16384 (0xFF init)
    __hip_bfloat16* W2b = (__hip_bfloat16*)(ws + 82320);   // 8192 bf16
    __hip_bfloat16* W3b = (__hip_bfloat16*)(ws + 86416);   // 32768 bf16
    unsigned* W1p = (unsigned*)(ws + 102800);              // 128 uint
    if (ws_size < (size_t)102928 * 4) return;

    hipMemsetAsync(d_ws, 0, (size_t)65936 * 4, stream);            // mom..maxk
    hipMemsetAsync((void*)mink, 0xFF, (size_t)16384 * 4, stream);  // mink

    k_prep<<<160, 256, 0, stream>>>(W2, W3, W2b, W3b);
    k_moments<<<1024, 256, 0, stream>>>(pcd, mom);
    k_fin1<<<1, 64, 0, stream>>>(mom, W1, fp_b1, g1, be1, W1p);
    k_pass1<<<2048, 256, 0, stream>>>(pcd, W1p, W2b, st2s, st2q);
    k_fin2<<<1, 128, 0, stream>>>(st2s, st2q, g2, be2, s2, t2);
    k_pass2<<<2048, 256, 0, stream>>>(pcd, W1p, W2b, s2, t2, W3b,
                                      st3s, st3q, maxk, mink);
    k_head<<<64, 128, 0, stream>>>(st3s, st3q, g3, be3, maxk, mink,
                                   Wfc, bfc, Wc1, bc1, Wc2, bc2,
                                   Wp1, bp1, Wp2, bp2, (float*)d_out);
}

// Round 7
// 293.760 us; speedup vs baseline: 2.3251x; 1.0862x over previous
//
#include <hip/hip_runtime.h>
#include <hip/hip_bf16.h>

#define NPTS 524288   // 64 * 8192
#define NBATCH 64

typedef __attribute__((ext_vector_type(8))) short bf16x8;
typedef __attribute__((ext_vector_type(4))) float f32x4;
typedef const float* __restrict__ fp;

__device__ __forceinline__ __hip_bfloat16 f2b(float v) { return __float2bfloat16(v); }
__device__ __forceinline__ unsigned bfbits(float v) {
    union { __hip_bfloat16 h; unsigned short s; } u; u.h = f2b(v); return (unsigned)u.s;
}
__device__ __forceinline__ unsigned pk2(float a, float b) {
    return bfbits(a) | (bfbits(b) << 16);
}
// unpack a pk2'd pair back to f32 (bf16 value = bits<<16)
__device__ __forceinline__ float lo2f(unsigned u) { return __uint_as_float(u << 16); }
__device__ __forceinline__ float hi2f(unsigned u) { return __uint_as_float(u & 0xffff0000u); }

// order-preserving float<->uint key for atomicMax/Min over signed floats
__device__ __forceinline__ unsigned fkey(float f) {
    unsigned u = __float_as_uint(f);
    return u ^ ((u & 0x80000000u) ? 0xFFFFFFFFu : 0x80000000u);
}
__device__ __forceinline__ float funkey(unsigned k) {
    unsigned u = (k & 0x80000000u) ? (k ^ 0x80000000u) : ~k;
    return __uint_as_float(u);
}

union U8 { bf16x8 v; __hip_bfloat16 e[8]; unsigned u[4]; };

static __device__ __forceinline__ f32x4 mfma16(bf16x8 a, bf16x8 b, f32x4 c) {
    return __builtin_amdgcn_mfma_f32_16x16x32_bf16(a, b, c, 0, 0, 0);
}

// ---------------- K0: W2/W3 -> bf16 (no deps, runs first) -------------------
__global__ void k_prep(fp W2, fp W3, __hip_bfloat16* __restrict__ W2b,
                       __hip_bfloat16* __restrict__ W3b)
{
    int i = blockIdx.x * blockDim.x + threadIdx.x;
    if (i < 8192) W2b[i] = f2b(W2[i]);
    const int j = i - 8192;
    if (j >= 0 && j < 32768) W3b[j] = f2b(W3[j]);
}

// ---------------- K1: second-order moments of pcd (analytic BN1 stats) ------
__launch_bounds__(256)
__global__ void k_moments(fp pcd, float* __restrict__ mom)
{
    float s[9];
#pragma unroll
    for (int i = 0; i < 9; ++i) s[i] = 0.f;
    const int stride = gridDim.x * blockDim.x;
    for (int p = blockIdx.x * blockDim.x + threadIdx.x; p < NPTS; p += stride) {
        const float x = pcd[3*p+0], y = pcd[3*p+1], z = pcd[3*p+2];
        s[0] += x; s[1] += y; s[2] += z;
        s[3] = fmaf(x, x, s[3]); s[4] = fmaf(x, y, s[4]); s[5] = fmaf(x, z, s[5]);
        s[6] = fmaf(y, y, s[6]); s[7] = fmaf(y, z, s[7]); s[8] = fmaf(z, z, s[8]);
    }
#pragma unroll
    for (int off = 1; off < 64; off <<= 1) {
#pragma unroll
        for (int i = 0; i < 9; ++i) s[i] += __shfl_xor(s[i], off);
    }
    __shared__ float red[4][9];
    const int lane = threadIdx.x & 63, wv = threadIdx.x >> 6;
    if (lane == 0) {
#pragma unroll
        for (int i = 0; i < 9; ++i) red[wv][i] = s[i];
    }
    __syncthreads();
    if (threadIdx.x < 9) {
        const int i = threadIdx.x;
        atomicAdd(&mom[i], red[0][i] + red[1][i] + red[2][i] + red[3][i]);
    }
}

// ---------------- K2: analytic BN1 folded straight into W1 ------------------
// W1p[c] = {s1*w0, s1*w1 | s1*w2, s1*b1 + t1} as 2 packed bf16 uints.
__global__ void k_fin1(const float* __restrict__ mom, fp W1, fp b1, fp g1, fp be1,
                       unsigned* __restrict__ W1p)
{
    const int c = threadIdx.x;  // 64 threads
    const float inv = 1.f / (float)NPTS;
    const float m0 = mom[0]*inv, m1 = mom[1]*inv, m2 = mom[2]*inv;
    const float c00 = mom[3]*inv - m0*m0, c01 = mom[4]*inv - m0*m1, c02 = mom[5]*inv - m0*m2;
    const float c11 = mom[6]*inv - m1*m1, c12 = mom[7]*inv - m1*m2, c22 = mom[8]*inv - m2*m2;
    const float w0 = W1[c*3+0], w1 = W1[c*3+1], w2 = W1[c*3+2];
    const float mu = w0*m0 + w1*m1 + w2*m2 + b1[c];
    float var = w0*w0*c00 + w1*w1*c11 + w2*w2*c22 + 2.f*(w0*w1*c01 + w0*w2*c02 + w1*w2*c12);
    var = fmaxf(var, 0.f);
    const float sc = g1[c] * rsqrtf(var + 1e-5f);
    const float sh = be1[c] - mu*sc;
    W1p[c*2+0] = pk2(w0*sc, w1*sc);
    W1p[c*2+1] = pk2(w2*sc, b1[c]*sc + sh);
}

// Per-lane VALU L1: lane (m,q) computes its OWN 16 L1 channels
// ch(t) = (t>>3)*32 + q*8 + (t&7) for point m -> directly forms the L2
// A-fragment a2f[ks].u[t2] = bf16 pair (ks*32+q*8+2t2, +1). No shuffles/LDS.
#define L1_DIRECT(a2f, px, py, pz)                                              \
    {                                                                           \
        float y[16];                                                            \
        _Pragma("unroll")                                                       \
        for (int t = 0; t < 16; ++t) {                                          \
            float v = fmaf(px, lo2f(wA[t]), hi2f(wB[t]));                       \
            v = fmaf(py, hi2f(wA[t]), v);                                       \
            v = fmaf(pz, lo2f(wB[t]), v);                                       \
            y[t] = fmaxf(v, 0.f);                                               \
        }                                                                       \
        _Pragma("unroll")                                                       \
        for (int ks = 0; ks < 2; ++ks)                                          \
            _Pragma("unroll")                                                   \
            for (int t2 = 0; t2 < 4; ++t2)                                      \
                a2f[ks].u[t2] = pk2(y[ks*8 + 2*t2], y[ks*8 + 2*t2 + 1]);        \
    }

#define LOAD_W1()                                                               \
    unsigned wA[16], wB[16];                                                    \
    _Pragma("unroll")                                                           \
    for (int t = 0; t < 16; ++t) {                                              \
        const int ch = (t >> 3)*32 + q*8 + (t & 7);                             \
        wA[t] = W1p[ch*2]; wB[t] = W1p[ch*2+1];                                 \
    }

// ---------------- Pass 1: L1 + L2, y2 raw stats (zero-DS main loop) ---------
// 2048 blocks x 256 thr; block = 32/batch, 4 unrolled iters x 64 points.
__launch_bounds__(256, 3)
__global__ void k_pass1(fp pcd, const unsigned* __restrict__ W1p,
                        const __hip_bfloat16* __restrict__ W2b,
                        float* __restrict__ st2s, float* __restrict__ st2q)
{
    __shared__ float red[1024];
    const int tid = threadIdx.x, wv = tid >> 6, lane = tid & 63;
    const int m = lane & 15, q = lane >> 4;
    const int batch = blockIdx.x >> 5, sub = blockIdx.x & 31;

    LOAD_W1()
    bf16x8 wb2[8][2];
#pragma unroll
    for (int nt = 0; nt < 8; ++nt) {
#pragma unroll
        for (int kk = 0; kk < 2; ++kk)
            wb2[nt][kk] = *(const bf16x8*)(W2b + (nt*16+m)*64 + kk*32 + q*8);
    }

    float s_acc[8], q_acc[8];
#pragma unroll
    for (int nt = 0; nt < 8; ++nt) { s_acc[nt] = 0.f; q_acc[nt] = 0.f; }

#pragma unroll
    for (int it = 0; it < 4; ++it) {
        const int p0 = batch*8192 + sub*256 + it*64 + wv*16;
        const float* pp = pcd + (size_t)(p0 + m) * 3;
        const float px = pp[0], py = pp[1], pz = pp[2];
        U8 a2f[2];
        L1_DIRECT(a2f, px, py, pz)
#pragma unroll
        for (int nt = 0; nt < 8; ++nt) {
            f32x4 c = mfma16(a2f[0].v, wb2[nt][0], (f32x4){0.f,0.f,0.f,0.f});
            c = mfma16(a2f[1].v, wb2[nt][1], c);
            s_acc[nt] += (c[0] + c[1]) + (c[2] + c[3]);
            q_acc[nt] = fmaf(c[0],c[0], fmaf(c[1],c[1], fmaf(c[2],c[2], fmaf(c[3],c[3], q_acc[nt]))));
        }
    }
#pragma unroll
    for (int nt = 0; nt < 8; ++nt) {
        s_acc[nt] += __shfl_xor(s_acc[nt], 16); q_acc[nt] += __shfl_xor(q_acc[nt], 16);
        s_acc[nt] += __shfl_xor(s_acc[nt], 32); q_acc[nt] += __shfl_xor(q_acc[nt], 32);
    }
    if (q == 0) {
#pragma unroll
        for (int nt = 0; nt < 8; ++nt) {
            red[wv*128 + nt*16 + m] = s_acc[nt];
            red[512 + wv*128 + nt*16 + m] = q_acc[nt];
        }
    }
    __syncthreads();
    if (tid < 128) {
        float s = 0.f, ss = 0.f;
#pragma unroll
        for (int w4 = 0; w4 < 4; ++w4) { s += red[w4*128 + tid]; ss += red[512 + w4*128 + tid]; }
        const int slot = blockIdx.x & 63;
        atomicAdd(&st2s[slot*128 + tid], s);
        atomicAdd(&st2q[slot*128 + tid], ss);
    }
}

// ---------------- K4: finalize BN2 (raw stats; b2 cancels in BN) ------------
__global__ void k_fin2(const float* __restrict__ sum, const float* __restrict__ sq,
                       fp g, fp be, float* __restrict__ sOut, float* __restrict__ tOut)
{
    const int ch = threadIdx.x;  // 128
    float s = 0.f, ss = 0.f;
    for (int slot = 0; slot < 64; ++slot) { s += sum[slot*128 + ch]; ss += sq[slot*128 + ch]; }
    const float inv = 1.f / (float)NPTS;
    const float mu = s * inv;
    const float var = fmaxf(ss * inv - mu*mu, 0.f);
    const float sc = g[ch] * rsqrtf(var + 1e-5f);
    sOut[ch] = sc;
    tOut[ch] = be[ch] - mu*sc;
}

// ---------------- Pass 2: phase A (front-end, no barriers) + 1 barrier +
// phase B (L3 over the whole 256-pt tile). Wave w owns W3 chs [w*64,w*64+64).
__launch_bounds__(256, 2)
__global__ void k_pass2(fp pcd, const unsigned* __restrict__ W1p,
                        const __hip_bfloat16* __restrict__ W2b,
                        const float* __restrict__ s2, const float* __restrict__ t2,
                        const __hip_bfloat16* __restrict__ W3b,
                        float* __restrict__ st3s, float* __restrict__ st3q,
                        unsigned* __restrict__ maxk, unsigned* __restrict__ mink)
{
    __shared__ alignas(16) __hip_bfloat16 x2s[256*136];   // 69.6 KB, stride 136
    const int tid = threadIdx.x, wv = tid >> 6, lane = tid & 63;
    const int m = lane & 15, q = lane >> 4;
    const int batch = blockIdx.x >> 5, sub = blockIdx.x & 31;

    LOAD_W1()
    bf16x8 wb2[8][2];
#pragma unroll
    for (int nt = 0; nt < 8; ++nt) {
#pragma unroll
        for (int kk = 0; kk < 2; ++kk)
            wb2[nt][kk] = *(const bf16x8*)(W2b + (nt*16+m)*64 + kk*32 + q*8);
    }
    float s2v[8], t2v[8];
#pragma unroll
    for (int nt = 0; nt < 8; ++nt) { s2v[nt] = s2[nt*16+m]; t2v[nt] = t2[nt*16+m]; }

    bf16x8 wb3[4][4];
#pragma unroll
    for (int nt = 0; nt < 4; ++nt) {
        const int ch3 = wv*64 + nt*16 + m;
#pragma unroll
        for (int ks = 0; ks < 4; ++ks)
            wb3[nt][ks] = *(const bf16x8*)(W3b + ch3*128 + ks*32 + q*8);
    }

    // ---- phase A: 4 independent front-end iterations, no barriers ----
#pragma unroll
    for (int it = 0; it < 4; ++it) {
        const int p0 = batch*8192 + sub*256 + it*64 + wv*16;
        const float* pp = pcd + (size_t)(p0 + m) * 3;
        const float px = pp[0], py = pp[1], pz = pp[2];
        U8 a2f[2];
        L1_DIRECT(a2f, px, py, pz)
#pragma unroll
        for (int nt = 0; nt < 8; ++nt) {
            f32x4 c = mfma16(a2f[0].v, wb2[nt][0], (f32x4){0.f,0.f,0.f,0.f});
            c = mfma16(a2f[1].v, wb2[nt][1], c);
#pragma unroll
            for (int r = 0; r < 4; ++r) {
                const float v = fmaxf(fmaf(c[r], s2v[nt], t2v[nt]), 0.f);
                const unsigned own = bfbits(v);
                const unsigned oth = (unsigned)__shfl_xor((int)own, 1);
                if ((m & 1) == 0) {
                    const int row = it*64 + wv*16 + q*4 + r;
                    *(unsigned*)&x2s[row*136 + nt*16 + m] = own | (oth << 16);
                }
            }
        }
    }
    __syncthreads();   // the ONLY barrier: all 256 x2 rows complete

    // ---- phase B: L3 over all 256 points x this wave's 64 channels ----
    float s3[4], q3[4], mx3[4], mn3[4];
#pragma unroll
    for (int nt = 0; nt < 4; ++nt) { s3[nt]=0.f; q3[nt]=0.f; mx3[nt]=-3.4e38f; mn3[nt]=3.4e38f; }

    for (int ms = 0; ms < 16; ++ms) {
        const int rowM = (ms*16 + m) * 136;
        bf16x8 a3[4];
#pragma unroll
        for (int ks = 0; ks < 4; ++ks)
            a3[ks] = *(const bf16x8*)&x2s[rowM + ks*32 + q*8];
#pragma unroll
        for (int nt = 0; nt < 4; ++nt) {
            f32x4 c = mfma16(a3[0], wb3[nt][0], (f32x4){0.f,0.f,0.f,0.f});
            c = mfma16(a3[1], wb3[nt][1], c);
            c = mfma16(a3[2], wb3[nt][2], c);
            c = mfma16(a3[3], wb3[nt][3], c);
            s3[nt] += (c[0] + c[1]) + (c[2] + c[3]);
            q3[nt] = fmaf(c[0],c[0], fmaf(c[1],c[1], fmaf(c[2],c[2], fmaf(c[3],c[3], q3[nt]))));
            mx3[nt] = fmaxf(fmaxf(c[0], c[1]), fmaxf(fmaxf(c[2], c[3]), mx3[nt]));
            mn3[nt] = fminf(fminf(c[0], c[1]), fminf(fminf(c[2], c[3]), mn3[nt]));
        }
    }
#pragma unroll
    for (int nt = 0; nt < 4; ++nt) {
        s3[nt] += __shfl_xor(s3[nt], 16);  q3[nt] += __shfl_xor(q3[nt], 16);
        mx3[nt] = fmaxf(mx3[nt], __shfl_xor(mx3[nt], 16));
        mn3[nt] = fminf(mn3[nt], __shfl_xor(mn3[nt], 16));
        s3[nt] += __shfl_xor(s3[nt], 32);  q3[nt] += __shfl_xor(q3[nt], 32);
        mx3[nt] = fmaxf(mx3[nt], __shfl_xor(mx3[nt], 32));
        mn3[nt] = fminf(mn3[nt], __shfl_xor(mn3[nt], 32));
    }
    if (q == 0) {
        const int slot = blockIdx.x & 63;
#pragma unroll
        for (int nt = 0; nt < 4; ++nt) {
            const int ch3 = wv*64 + nt*16 + m;
            atomicAdd(&st3s[slot*256 + ch3], s3[nt]);
            atomicAdd(&st3q[slot*256 + ch3], q3[nt]);
            atomicMax(&maxk[batch*256 + ch3], fkey(mx3[nt]));
            atomicMin(&mink[batch*256 + ch3], fkey(mn3[nt]));
        }
    }
}

// ---------------- K8: BN3-fold + heads + QP (1 block / batch) ---------------
__launch_bounds__(128)
__global__ void k_head(const float* __restrict__ st3s, const float* __restrict__ st3q,
                       fp g3, fp be3,
                       const unsigned* __restrict__ maxk, const unsigned* __restrict__ mink,
                       fp Wfc, fp bfc, fp Wc1, fp bc1, fp Wc2, fp bc2,
                       fp Wp1, fp bp1, fp Wp2, fp bp2,
                       float* __restrict__ out)
{
    __shared__ float pf[256], ft[128], hcs[128], hps[64], ocs[48], nrm[36], hS[12], pp[8];
    const int bb = blockIdx.x, tid = threadIdx.x;
#pragma unroll
    for (int h = 0; h < 2; ++h) {
        const int ch = tid + h*128;
        float s = 0.f, ss = 0.f;
        for (int slot = 0; slot < 64; ++slot) { s += st3s[slot*256 + ch]; ss += st3q[slot*256 + ch]; }
        const float inv = 1.f / (float)NPTS;
        const float mu = s * inv;
        const float var = fmaxf(ss * inv - mu*mu, 0.f);
        const float sc = g3[ch] * rsqrtf(var + 1e-5f);
        const float sh = be3[ch] - mu*sc;
        const float pick = (sc >= 0.f) ? funkey(maxk[bb*256 + ch]) : funkey(mink[bb*256 + ch]);
        pf[ch] = fmaxf(fmaf(pick, sc, sh), 0.f);
    }
    __syncthreads();
    {
        float a = bfc[tid];
        const float* wr = Wfc + tid*256;
        for (int k = 0; k < 256; ++k) a = fmaf(pf[k], wr[k], a);
        ft[tid] = a;
    }
    __syncthreads();
    {
        float a = bc1[tid];
        const float* wr = Wc1 + tid*128;
        for (int k = 0; k < 128; ++k) a = fmaf(ft[k], wr[k], a);
        hcs[tid] = fmaxf(a, 0.f);
    }
    if (tid < 64) {
        float a = bp1[tid];
        const float* wr = Wp1 + tid*128;
        for (int k = 0; k < 128; ++k) a = fmaf(ft[k], wr[k], a);
        hps[tid] = fmaxf(a, 0.f);
    }
    __syncthreads();
    if (tid < 48) {
        float a = bc2[tid];
        const float* wr = Wc2 + tid*128;
        for (int k = 0; k < 128; ++k) a = fmaf(hcs[k], wr[k], a);
        ocs[tid] = a;
    }
    if (tid < 7) {
        float a = bp2[tid];
        const float* wr = Wp2 + tid*64;
        for (int k = 0; k < 64; ++k) a = fmaf(hps[k], wr[k], a);
        const float sc = (tid < 3) ? 0.1f : ((tid < 6) ? 1.57f : 0.05f);
        pp[tid] = tanhf(a) * sc;
    }
    __syncthreads();
    if (tid < 12) {
        float nx = ocs[tid*4+0], ny = ocs[tid*4+1], nz = ocs[tid*4+2];
        const float nn = fmaxf(sqrtf(nx*nx + ny*ny + nz*nz), 1e-12f);
        const float inv = 1.f / nn;
        nx *= inv; ny *= inv; nz *= inv;
        nrm[tid*3+0] = nx; nrm[tid*3+1] = ny; nrm[tid*3+2] = nz;
        const float xx = ocs[tid*4+3];
        hS[tid] = ((xx > 20.f) ? xx : log1pf(expf(xx))) + 0.005f;
    }
    __syncthreads();

    const int lane = tid & 63;
    const int c = (lane < 12) ? lane : 11;
    const float n0 = nrm[c*3+0], n1 = nrm[c*3+1], n2 = nrm[c*3+2];
    float Mrow[12];
    float trace = 0.f;
#pragma unroll
    for (int d = 0; d < 12; ++d) {
        const float d0 = nrm[d*3+0], d1 = nrm[d*3+1], d2 = nrm[d*3+2];
        Mrow[d] = n0*d0 + n1*d1 + n2*d2 + ((d == lane) ? 5e-4f : 0.f);
        trace += d0*d0 + d1*d1 + d2*d2;
    }
    const float alpha = 1.f / (trace + 12.f*5e-4f);
    const float qc = n0*pp[0] + n1*pp[1] + n2*pp[2] - hS[c];
    float lam = 0.f;
    for (int it = 0; it < 500; ++it) {
        const float l0 = __shfl(lam, 0),  l1 = __shfl(lam, 1),  l2 = __shfl(lam, 2);
        const float l3 = __shfl(lam, 3),  l4 = __shfl(lam, 4),  l5 = __shfl(lam, 5);
        const float l6 = __shfl(lam, 6),  l7 = __shfl(lam, 7),  l8 = __shfl(lam, 8);
        const float l9 = __shfl(lam, 9),  l10 = __shfl(lam, 10), l11 = __shfl(lam, 11);
        const float g0 = fmaf(Mrow[0], l0, fmaf(Mrow[3], l3, fmaf(Mrow[6], l6, Mrow[9]*l9)));
        const float g1 = fmaf(Mrow[1], l1, fmaf(Mrow[4], l4, fmaf(Mrow[7], l7, Mrow[10]*l10)));
        const float g2 = fmaf(Mrow[2], l2, fmaf(Mrow[5], l5, fmaf(Mrow[8], l8, Mrow[11]*l11)));
        lam = fmaxf(fmaf(-alpha, g0 + g1 + g2 - qc, lam), 0.f);
    }
    float v0 = (lane < 12) ? n0*lam : 0.f;
    float v1 = (lane < 12) ? n1*lam : 0.f;
    float v2 = (lane < 12) ? n2*lam : 0.f;
#pragma unroll
    for (int off = 1; off <= 8; off <<= 1) {
        v0 += __shfl_xor(v0, off);
        v1 += __shfl_xor(v1, off);
        v2 += __shfl_xor(v2, off);
    }
    if (tid < 7) {
        float z;
        if (tid == 0) z = pp[0] - v0;
        else if (tid == 1) z = pp[1] - v1;
        else if (tid == 2) z = pp[2] - v2;
        else z = pp[tid];
        out[bb*7 + tid] = z;
    }
    if (tid < 36) out[448 + bb*36 + tid] = nrm[tid];
    if (tid < 12) out[2752 + bb*12 + tid] = hS[tid];
    if (tid < 7)  out[3520 + bb*7 + tid] = pp[tid];
}

// ---------------- host ------------------------------------------------------
extern "C" void kernel_launch(void* const* d_in, const int* in_sizes, int n_in,
                              void* d_out, int out_size, void* d_ws, size_t ws_size,
                              hipStream_t stream) {
    fp pcd = (fp)d_in[0];
    fp W1 = (fp)d_in[1],  b1 = (fp)d_in[2],  g1 = (fp)d_in[3],  be1 = (fp)d_in[4];
    fp W2 = (fp)d_in[5],  g2 = (fp)d_in[7],  be2 = (fp)d_in[8];
    fp W3 = (fp)d_in[9],  g3 = (fp)d_in[11], be3 = (fp)d_in[12];
    fp Wfc = (fp)d_in[13], bfc = (fp)d_in[14];
    fp Wc1 = (fp)d_in[15], bc1 = (fp)d_in[16];
    fp Wc2 = (fp)d_in[17], bc2 = (fp)d_in[18];
    fp Wp1 = (fp)d_in[19], bp1 = (fp)d_in[20];
    fp Wp2 = (fp)d_in[21], bp2 = (fp)d_in[22];
    // b2 (d_in[6]) / b3 (d_in[10]) cancel analytically in BN

    float* ws = (float*)d_ws;
    float* mom  = ws + 0;           // 16
    float* s2   = ws + 144;         // 128
    float* t2   = ws + 272;         // 128
    float* st2s = ws + 400;         // 64*128 = 8192
    float* st2q = ws + 8592;        // 8192
    float* st3s = ws + 16784;       // 64*256 = 16384
    float* st3q = ws + 33168;       // 16384
    unsigned* maxk = (unsigned*)(ws + 49552);   // 16384 (0-init ok: keys>0)
    unsigned* mink = (unsigned*)(ws + 65936);   // 16384 (0xFF init)
    __hip_bfloat16* W2b = (__hip_bfloat16*)(ws + 82320);   // 8192 bf16
    __hip_bfloat16* W3b = (__hip_bfloat16*)(ws + 86416);   // 32768 bf16
    unsigned* W1p = (unsigned*)(ws + 102800);              // 128 uint
    if (ws_size < (size_t)102928 * 4) return;

    hipMemsetAsync(d_ws, 0, (size_t)65936 * 4, stream);            // mom..maxk
    hipMemsetAsync((void*)mink, 0xFF, (size_t)16384 * 4, stream);  // mink

    k_prep<<<160, 256, 0, stream>>>(W2, W3, W2b, W3b);
    k_moments<<<1024, 256, 0, stream>>>(pcd, mom);
    k_fin1<<<1, 64, 0, stream>>>(mom, W1, b1, g1, be1, W1p);
    k_pass1<<<2048, 256, 0, stream>>>(pcd, W1p, W2b, st2s, st2q);
    k_fin2<<<1, 128, 0, stream>>>(st2s, st2q, g2, be2, s2, t2);
    k_pass2<<<2048, 256, 0, stream>>>(pcd, W1p, W2b, s2, t2, W3b,
                                      st3s, st3q, maxk, mink);
    k_head<<<64, 128, 0, stream>>>(st3s, st3q, g3, be3, maxk, mink,
                                   Wfc, bfc, Wc1, bc1, Wc2, bc2,
                                   Wp1, bp1, Wp2, bp2, (float*)d_out);
}